// Round 7
// baseline (591.640 us; speedup 1.0000x reference)
//
#include <hip/hip_runtime.h>
#include <math.h>

// Problem constants
#define BATCH 1024
#define NA 10
#define NEN 10
#define NALY 9
#define NAG (BATCH*NA)          // 10240
#define NEE (NAG*NEN)           // 102400
#define NAE (NAG*NALY)          // 92160
#define EPSF 1e-5f

// f64 replicated qbn-sum buffers (16 replicas), at start of ws (double units)
#define DOFF_SE1 0
#define DOFF_SE2 1024
#define DOFF_SA1 2048
#define DOFF_SA2 3072
#define DOFF_SF1 4096
#define DOFF_SF2 5120
#define DOFF_SIE1 6144
#define DOFF_SIE2 7168
#define DOFF_SIA1 8192
#define DOFF_SIA2 9216
#define DOFF_SIE3 10240   // 16 replicas x stride 8
#define DOFF_SIA3 10368
#define NDOUBLES 16384

#define NBLK_BE (NEE/8)    // 12800
#define NBLK_BA (NAE/8)    // 11520
#define NBLK_PE64 (NEE/64) // 1600
#define NBLK_PA64 (NAE/64) // 1440

__device__ __forceinline__ double sum16vd(const double* __restrict__ S, int ch) {
    double s = 0.0;
#pragma unroll
    for (int r = 0; r < 16; ++r) s += S[r*64 + ch];
    return s;
}
__device__ __forceinline__ double sum16sd8(const double* __restrict__ S) {
    double s = 0.0;
#pragma unroll
    for (int r = 0; r < 16; ++r) s += S[r*8];
    return s;
}
__device__ __forceinline__ float qbn_s(const double* __restrict__ S, int ch, double invRows) {
    float m = (float)(sum16vd(S, ch)*invRows);
    return sqrtf(m + EPSF);
}
__device__ __forceinline__ void red_to_S(const double* red, double* S, int bid, int tid) {
    if (tid < 64) {
        double v = red[tid] + red[tid+64] + red[tid+128] + red[tid+192];
        atomicAdd(&S[(bid & 15)*64 + tid], v);
    }
}
// np-lattice pair mod^2: fl(fl(x0^2)+fl(x1^2)) (no FMA contraction)
__device__ __forceinline__ float pair_m2(float x0, float x1) {
    return __fadd_rn(__fmul_rn(x0,x0), __fmul_rn(x1,x1));
}
// qrelu coeff: bit-identical to mod/fmaxf(1,mod) for finite mod:
//   mod<=1 -> mod/1 == mod exactly; mod>1 -> mod/mod == 1.0f exactly.
__device__ __forceinline__ float qcoef(float mod) {
    return fminf(mod, 1.0f);
}

// ---- build_vec + layer1 GEMM, E and A fused in one launch.
//      Per-output FP sequence identical (REVERSED k, FROZEN). ----
__global__ __launch_bounds__(256) void k_build_both(
    const float* __restrict__ ef, const float* __restrict__ af,
    const float* __restrict__ own,
    const float* __restrict__ We1, const float* __restrict__ Wa1,
    float* __restrict__ XE, float* __restrict__ XA,
    double* __restrict__ SE1, double* __restrict__ SA1)
{
    bool isA = (blockIdx.x >= NBLK_BE);
    int blk = isA ? (blockIdx.x - NBLK_BE) : blockIdx.x;
    const float* feats = isA ? af : ef;
    const float* W1    = isA ? Wa1 : We1;
    float* X           = isA ? XA : XE;
    double* S1         = isA ? SA1 : SE1;
    int nEntPerAgent   = isA ? NALY : NEN;

    __shared__ float wlds[19*64];
    __shared__ float gpc[16][19];     // (el*2+c, k): pc * g  precomputed
    __shared__ double red[256];
    int tid = threadIdx.x;
    for (int i = tid; i < 19*64; i += 256) wlds[i] = W1[i];
    if (tid < 152) {
        int el = tid / 19, chg = tid % 19;
        int ent = blk*8 + el;
        const float* f = feats + (size_t)ent*9;
        int agent = ent / nEntPerAgent;
        float px = f[2], py = f[3];
        float pm = sqrtf(__fadd_rn(__fmul_rn(px,px), __fmul_rn(py,py)));
        float val;
        if (chg == 0) val = 1.f;
        else if (chg < 8) {
            int j = chg - 1;
            int fi = (j < 2) ? j : (j + 2);
            float o = f[fi];
            float om = sqrtf(__fmul_rn(__fmul_rn(2.0f,o),o));
            val = (pm == 0.f) ? 0.f : __fdiv_rn(om, pm);
        } else {
            float o = own[(size_t)agent*11 + (chg-8)];
            float t = __fmul_rn(o,o);
            float om = sqrtf(__fadd_rn(t,t));
            val = (pm == 0.f) ? 0.f : __fdiv_rn(om, pm);
        }
        // same bits as the old per-lane __fmul_rn(pc, g[el][k])
        gpc[el*2 + 0][chg] = __fmul_rn(px, val);
        gpc[el*2 + 1][chg] = __fmul_rn(py, val);
    }
    __syncthreads();
    int l = tid >> 7, c = (tid >> 6) & 1, ch = tid & 63;
    float wreg[19];
#pragma unroll
    for (int k = 0; k < 19; ++k) wreg[k] = wlds[k*64+ch];
    double lr = 0.0;
#pragma unroll
    for (int i = 0; i < 4; ++i) {
        int el = l + 2*i;
        int ent = blk*8 + el;
        int row = el*2 + c;
        float acc = 0.f;
#pragma unroll
        for (int k = 18; k >= 0; --k) {            // REVERSED k (frozen)
            acc = fmaf(gpc[row][k], wreg[k], acc);
        }
        X[(size_t)ent*128 + c*64 + ch] = acc;
        lr += (double)acc * (double)acc;
    }
    red[tid] = lr;
    __syncthreads();
    red_to_S(red, S1, blk, tid);
}

// ---- pair-layer core: 512 threads, 64 rows/block, 2 rows/thread.
//      dredw aliased into ybuf (barrier after GEMM makes it race-free).
//      Each output's fmaf chain (REVERSED k) is unchanged bit-for-bit. ----
__device__ __forceinline__ void pair_layer_body(
    float* __restrict__ X, const double* __restrict__ Sin, double* __restrict__ Sout,
    const float* __restrict__ W, double invRows, int blk)
{
    __shared__ float wlds[4096];
    __shared__ __align__(16) float ybuf[64][132];
    __shared__ float ss[64];
    double* dredw = (double*)&ybuf[0][0];   // 8 waves x 64 ch = 4 KB, aliased
    int tid = threadIdx.x;
    for (int i = tid; i < 4096; i += 512) wlds[i] = W[i];
    if (tid < 64) ss[tid] = qbn_s(Sin, tid, invRows);
    __syncthreads();
    int rl = tid >> 4;                 // 0..31
    int ch0 = (tid & 15) * 4;
#pragma unroll
    for (int h = 0; h < 2; ++h) {
        int r = rl + h*32;
        size_t row = (size_t)blk*64 + r;
        float4 xv0 = *(const float4*)&X[row*128 + ch0];
        float4 xv1 = *(const float4*)&X[row*128 + 64 + ch0];
        float xs0[4] = {xv0.x,xv0.y,xv0.z,xv0.w};
        float xs1[4] = {xv1.x,xv1.y,xv1.z,xv1.w};
        float y0[4], y1[4];
#pragma unroll
        for (int i = 0; i < 4; ++i) {
            float s = ss[ch0+i];
            float u0 = xs0[i]/s, u1 = xs1[i]/s;
            float mod = sqrtf(pair_m2(u0,u1));
            float cf = qcoef(mod);
            y0[i] = __fmul_rn(u0,cf);
            y1[i] = __fmul_rn(u1,cf);
        }
        *(float4*)&ybuf[r][2*ch0]     = make_float4(y0[0],y1[0],y0[1],y1[1]);
        *(float4*)&ybuf[r][2*ch0 + 4] = make_float4(y0[2],y1[2],y0[3],y1[3]);
    }
    __syncthreads();
    float a0[4] = {0.f,0.f,0.f,0.f};
    float a1[4] = {0.f,0.f,0.f,0.f};
    float c0[4] = {0.f,0.f,0.f,0.f};
    float c1[4] = {0.f,0.f,0.f,0.f};
#pragma unroll
    for (int k = 63; k >= 1; k -= 2) {           // REVERSED k (frozen)
        float4 wk  = *(const float4*)&wlds[k*64 + ch0];
        float4 wk1 = *(const float4*)&wlds[(k-1)*64 + ch0];
        float4 ya  = *(const float4*)&ybuf[rl][2*k - 2];
        float4 yb  = *(const float4*)&ybuf[rl+32][2*k - 2];
        float wkv[4]  = {wk.x,wk.y,wk.z,wk.w};
        float wk1v[4] = {wk1.x,wk1.y,wk1.z,wk1.w};
#pragma unroll
        for (int i = 0; i < 4; ++i) {
            a0[i] = fmaf(ya.z, wkv[i], a0[i]);
            a1[i] = fmaf(ya.w, wkv[i], a1[i]);
        }
#pragma unroll
        for (int i = 0; i < 4; ++i) {
            a0[i] = fmaf(ya.x, wk1v[i], a0[i]);
            a1[i] = fmaf(ya.y, wk1v[i], a1[i]);
        }
#pragma unroll
        for (int i = 0; i < 4; ++i) {
            c0[i] = fmaf(yb.z, wkv[i], c0[i]);
            c1[i] = fmaf(yb.w, wkv[i], c1[i]);
        }
#pragma unroll
        for (int i = 0; i < 4; ++i) {
            c0[i] = fmaf(yb.x, wk1v[i], c0[i]);
            c1[i] = fmaf(yb.y, wk1v[i], c1[i]);
        }
    }
    size_t rowA = (size_t)blk*64 + rl;
    size_t rowB = rowA + 32;
    *(float4*)&X[rowA*128 + ch0]      = make_float4(a0[0],a0[1],a0[2],a0[3]);
    *(float4*)&X[rowA*128 + 64 + ch0] = make_float4(a1[0],a1[1],a1[2],a1[3]);
    *(float4*)&X[rowB*128 + ch0]      = make_float4(c0[0],c0[1],c0[2],c0[3]);
    *(float4*)&X[rowB*128 + 64 + ch0] = make_float4(c1[0],c1[1],c1[2],c1[3]);
    __syncthreads();   // ybuf reads done; safe to reuse as dredw
    {
        int wv = tid >> 6;             // 0..7
#pragma unroll
        for (int i = 0; i < 4; ++i) {
            double d = (double)a0[i]*a0[i] + (double)a1[i]*a1[i]
                     + (double)c0[i]*c0[i] + (double)c1[i]*c1[i];
            d += __shfl_xor(d, 16, 64);
            d += __shfl_xor(d, 32, 64);
            if ((tid & 48) == 0) dredw[wv*64 + ch0+i] = d;
        }
    }
    __syncthreads();
    if (tid < 64) {
        double v = 0.0;
#pragma unroll
        for (int w = 0; w < 8; ++w) v += dredw[w*64 + tid];
        atomicAdd(&Sout[(blk & 15)*64 + tid], v);
    }
}

// ---- pair layer for two X-streams in one launch (split at NBLK_PE64). ----
__global__ __launch_bounds__(512) void k_pair_both(
    float* __restrict__ XE, const double* __restrict__ SE1, double* __restrict__ SE2,
    const float* __restrict__ We2, double invRe,
    float* __restrict__ XA, const double* __restrict__ SA1, double* __restrict__ SA2,
    const float* __restrict__ Wa2, double invRa)
{
    if (blockIdx.x < NBLK_PE64)
        pair_layer_body(XE, SE1, SE2, We2, invRe, blockIdx.x);
    else
        pair_layer_body(XA, SA1, SA2, Wa2, invRa, blockIdx.x - NBLK_PE64);
}

// ---- generic pair layer (F1). ----
__global__ __launch_bounds__(512) void k_pair_layer(
    float* __restrict__ X, const double* __restrict__ Sin, double* __restrict__ Sout,
    const float* __restrict__ W, double invRows)
{
    pair_layer_body(X, Sin, Sout, W, invRows, blockIdx.x);
}

// ---- Finalize (E only): y = qrelu(qbn(x)) in place + ESC = pair_m2. ----
__global__ __launch_bounds__(256) void k_finalize_pair(
    float* __restrict__ X, const double* __restrict__ S2, double invRows,
    float* __restrict__ ESC)
{
    __shared__ float ss[64];
    if (threadIdx.x < 64) ss[threadIdx.x] = qbn_s(S2, threadIdx.x, invRows);
    int t = blockIdx.x*256 + threadIdx.x;
    int rl = t >> 4;              // (ent*2 + c) row index
    int ch0 = (t & 15) * 4;
    size_t base    = (size_t)rl*64 + ch0;
    size_t partner = (size_t)(rl ^ 1)*64 + ch0;
    float4 xv  = *(const float4*)&X[base];
    float4 xov = *(const float4*)&X[partner];
    __syncthreads();
    float xs[4]  = {xv.x,xv.y,xv.z,xv.w};
    float xos[4] = {xov.x,xov.y,xov.z,xov.w};
    float r[4], esc[4];
    int c = rl & 1;
#pragma unroll
    for (int i = 0; i < 4; ++i) {
        float s = ss[ch0+i];
        float u  = xs[i]/s;
        float uo = xos[i]/s;
        float u0 = (c==0) ? u : uo, u1 = (c==0) ? uo : u;
        float mod = sqrtf(pair_m2(u0,u1));
        float cf = qcoef(mod);
        r[i] = __fmul_rn(u, cf);
        if (c == 0) {
            float y1v = __fmul_rn(uo, cf);   // identical bits to partner's write
            esc[i] = pair_m2(r[i], y1v);
        }
    }
    *(float4*)&X[base] = make_float4(r[0],r[1],r[2],r[3]);
    if (c == 0) {
        int ent = rl >> 1;
        *(float4*)&ESC[(size_t)ent*64 + ch0] = make_float4(esc[0],esc[1],esc[2],esc[3]);
    }
}

// ---- Pool + f1 GEMM, ally finalize fused (identical op sequence). ----
__global__ __launch_bounds__(256) void k_pool_f1(
    const float* __restrict__ XE, const float* __restrict__ XAraw,
    const double* __restrict__ SA2, double invRa,
    const float* __restrict__ Wf1, float* __restrict__ F1, double* __restrict__ Sf1)
{
    __shared__ float wlds[4096];
    __shared__ float v[4][2][64];
    __shared__ float ssa[64];
    __shared__ double red[256];
    int tid = threadIdx.x;
    for (int i = tid; i < 4096; i += 256) wlds[i] = Wf1[i];
    if (tid < 64) ssa[tid] = qbn_s(SA2, tid, invRa);
    __syncthreads();
    int grp = tid>>6, ch = tid&63;
    int agent = blockIdx.x*4 + grp;
    float best = -1.f, v0 = 0.f, v1 = 0.f;
    for (int e = 0; e < NEN; ++e) {
        size_t b = (size_t)(agent*NEN+e)*128;
        float x0 = XE[b+ch], x1 = XE[b+64+ch];
        float m2 = pair_m2(x0,x1);
        if (m2 > best) { best = m2; v0 = x0; v1 = x1; }
    }
    float sa = ssa[ch];
    for (int l = 0; l < NALY; ++l) {
        size_t b = (size_t)(agent*NALY+l)*128;
        float r0 = XAraw[b+ch], r1 = XAraw[b+64+ch];
        float u0 = r0/sa, u1 = r1/sa;
        float modf = sqrtf(pair_m2(u0,u1));
        float cff = qcoef(modf);
        float x0 = __fmul_rn(u0,cff), x1 = __fmul_rn(u1,cff);
        float m2 = pair_m2(x0,x1);
        if (m2 > best) { best = m2; v0 = x0; v1 = x1; }
    }
    v[grp][0][ch] = v0; v[grp][1][ch] = v1;
    __syncthreads();
    float a0 = 0.f, a1 = 0.f;
#pragma unroll
    for (int k = 0; k < 64; ++k) {
        float w = wlds[k*64+ch];
        a0 = fmaf(v[grp][0][k], w, a0);
        a1 = fmaf(v[grp][1][k], w, a1);
    }
    F1[(size_t)agent*128+ch] = a0; F1[(size_t)agent*128+64+ch] = a1;
    red[tid] = (double)a0*a0 + (double)a1*a1;
    __syncthreads();
    red_to_S(red, Sf1, blockIdx.x, tid);
}

// ---- vf finalize + SFb + VT = vf @ W1top for both imp chains
//      + ATtop = b_at1 + sf @ W_at1[0:64] (hoisted attn layer1 top half).
//      ATtop overwrites F1 in place (dead after; reads precede barrier). ----
__global__ __launch_bounds__(256) void k_vf_vtop(
    float* __restrict__ F1, const double* __restrict__ Sf2,
    float* __restrict__ SFb,
    const float* __restrict__ Wie1, const float* __restrict__ Wia1,
    const float* __restrict__ Wat1, const float* __restrict__ bat1,
    float* __restrict__ VTie, float* __restrict__ VTia, double invRows)
{
    __shared__ float wie[4096];
    __shared__ float wia[4096];
    __shared__ float vf[4][2][64];
    __shared__ float sfv[4][64];
    int tid = threadIdx.x;
    for (int i = tid; i < 4096; i += 256) { wie[i] = Wie1[i]; wia[i] = Wia1[i]; }
    int grp = tid>>6, ch = tid&63;
    int agent = blockIdx.x*4 + grp;
    float x0 = F1[(size_t)agent*128+ch], x1 = F1[(size_t)agent*128+64+ch];
    float s = qbn_s(Sf2, ch, invRows);
    float u0 = x0/s, u1 = x1/s;
    float mod = sqrtf(pair_m2(u0,u1));
    float cf = qcoef(mod);
    float y0 = __fmul_rn(u0,cf), y1 = __fmul_rn(u1,cf);
    vf[grp][0][ch] = y0; vf[grp][1][ch] = y1;
    float sf = pair_m2(y0,y1);
    SFb[(size_t)agent*64+ch] = sf;
    sfv[grp][ch] = sf;
    __syncthreads();
    float a0=0.f,a1=0.f,b0=0.f,b1=0.f;
    float at0 = bat1[ch], at1 = bat1[64+ch];
#pragma unroll
    for (int k = 0; k < 64; ++k) {
        float f0 = vf[grp][0][k], f1 = vf[grp][1][k];
        a0 = fmaf(f0, wie[k*64+ch], a0); a1 = fmaf(f1, wie[k*64+ch], a1);
        b0 = fmaf(f0, wia[k*64+ch], b0); b1 = fmaf(f1, wia[k*64+ch], b1);
        float sv = sfv[grp][k];
        at0 = fmaf(sv, Wat1[k*128 + ch], at0);
        at1 = fmaf(sv, Wat1[k*128 + 64 + ch], at1);
    }
    VTie[(size_t)agent*128+ch] = a0; VTie[(size_t)agent*128+64+ch] = a1;
    VTia[(size_t)agent*128+ch] = b0; VTia[(size_t)agent*128+64+ch] = b1;
    F1[(size_t)agent*128+ch] = at0; F1[(size_t)agent*128+64+ch] = at1;
}

// ---- imp layer1 BOTH chains: 512 threads, 32 ents/block, 2 rows/thread.
//      dredw aliased into xt (barrier after GEMM). Per-output chains frozen. ----
__global__ __launch_bounds__(512) void k_imp1_both(
    float* __restrict__ XE,
    const float* __restrict__ VTe, const float* __restrict__ VTa,
    const float* __restrict__ W1e, const float* __restrict__ W1a,
    float* __restrict__ XIe,
    double* __restrict__ S1e, double* __restrict__ S1a)
{
    __shared__ float wldsE[4096];
    __shared__ float wldsA[4096];
    __shared__ __align__(16) float xt[64][68];
    double* dredwE = (double*)&xt[0][0];        // 8 waves x 64 ch
    double* dredwA = dredwE + 512;              // next 4 KB
    int tid = threadIdx.x;
    for (int i = tid; i < 4096; i += 512) { wldsE[i] = W1e[4096 + i]; wldsA[i] = W1a[4096 + i]; }
#pragma unroll
    for (int i = 0; i < 2; ++i) {
        int fidx = tid + i*512;               // float4 index 0..1023
        int r = fidx >> 4;                    // row 0..63 (= ent_local*2 + c)
        int kq = (fidx & 15) * 4;
        float4 t4 = *(const float4*)&XE[(size_t)blockIdx.x*4096 + (size_t)fidx*4];
        *(float4*)&xt[r][kq] = t4;
    }
    __syncthreads();
    int rl = tid >> 4;                        // 0..31
    int ch0 = (tid & 15) * 4;
    int entA = blockIdx.x*32 + (rl >> 1);     // rows rl      -> ents 0..15
    int entB = entA + 16;                     // rows rl+32   -> ents 16..31
    int c = rl & 1;
    int agentA = entA / NEN, agentB = entB / NEN;
    float4 vteA = *(const float4*)&VTe[(size_t)agentA*128 + c*64 + ch0];
    float4 vtaA = *(const float4*)&VTa[(size_t)agentA*128 + c*64 + ch0];
    float4 vteB = *(const float4*)&VTe[(size_t)agentB*128 + c*64 + ch0];
    float4 vtaB = *(const float4*)&VTa[(size_t)agentB*128 + c*64 + ch0];
    float accEA[4] = {vteA.x, vteA.y, vteA.z, vteA.w};
    float accAA[4] = {vtaA.x, vtaA.y, vtaA.z, vtaA.w};
    float accEB[4] = {vteB.x, vteB.y, vteB.z, vteB.w};
    float accAB[4] = {vtaB.x, vtaB.y, vtaB.z, vtaB.w};
#pragma unroll
    for (int k = 0; k < 64; k += 4) {
        float4 xa4 = *(const float4*)&xt[rl][k];
        float4 xb4 = *(const float4*)&xt[rl+32][k];
        float xa[4] = {xa4.x, xa4.y, xa4.z, xa4.w};
        float xb[4] = {xb4.x, xb4.y, xb4.z, xb4.w};
#pragma unroll
        for (int kk = 0; kk < 4; ++kk) {
            float4 we = *(const float4*)&wldsE[(k+kk)*64 + ch0];
            accEA[0] = fmaf(xa[kk], we.x, accEA[0]);
            accEA[1] = fmaf(xa[kk], we.y, accEA[1]);
            accEA[2] = fmaf(xa[kk], we.z, accEA[2]);
            accEA[3] = fmaf(xa[kk], we.w, accEA[3]);
            accEB[0] = fmaf(xb[kk], we.x, accEB[0]);
            accEB[1] = fmaf(xb[kk], we.y, accEB[1]);
            accEB[2] = fmaf(xb[kk], we.z, accEB[2]);
            accEB[3] = fmaf(xb[kk], we.w, accEB[3]);
            float4 wa = *(const float4*)&wldsA[(k+kk)*64 + ch0];
            accAA[0] = fmaf(xa[kk], wa.x, accAA[0]);
            accAA[1] = fmaf(xa[kk], wa.y, accAA[1]);
            accAA[2] = fmaf(xa[kk], wa.z, accAA[2]);
            accAA[3] = fmaf(xa[kk], wa.w, accAA[3]);
            accAB[0] = fmaf(xb[kk], wa.x, accAB[0]);
            accAB[1] = fmaf(xb[kk], wa.y, accAB[1]);
            accAB[2] = fmaf(xb[kk], wa.z, accAB[2]);
            accAB[3] = fmaf(xb[kk], wa.w, accAB[3]);
        }
    }
    *(float4*)&XIe[(size_t)entA*128 + c*64 + ch0] = make_float4(accEA[0],accEA[1],accEA[2],accEA[3]);
    *(float4*)&XIe[(size_t)entB*128 + c*64 + ch0] = make_float4(accEB[0],accEB[1],accEB[2],accEB[3]);
    *(float4*)&XE [(size_t)entA*128 + c*64 + ch0] = make_float4(accAA[0],accAA[1],accAA[2],accAA[3]);
    *(float4*)&XE [(size_t)entB*128 + c*64 + ch0] = make_float4(accAB[0],accAB[1],accAB[2],accAB[3]);
    __syncthreads();   // xt reads done; safe to reuse as dredw
    int wv = tid >> 6;
#pragma unroll
    for (int i = 0; i < 4; ++i) {
        double dE = (double)accEA[i]*accEA[i] + (double)accEB[i]*accEB[i];
        dE += __shfl_xor(dE, 16, 64);
        dE += __shfl_xor(dE, 32, 64);
        double dA = (double)accAA[i]*accAA[i] + (double)accAB[i]*accAB[i];
        dA += __shfl_xor(dA, 16, 64);
        dA += __shfl_xor(dA, 32, 64);
        if ((tid & 48) == 0) {
            dredwE[wv*64 + ch0+i] = dE;
            dredwA[wv*64 + ch0+i] = dA;
        }
    }
    __syncthreads();
    if (tid < 64) {
        double vE = 0.0, vA = 0.0;
#pragma unroll
        for (int w = 0; w < 8; ++w) { vE += dredwE[w*64 + tid]; vA += dredwA[w*64 + tid]; }
        atomicAdd(&S1e[(blockIdx.x & 15)*64 + tid], vE);
        atomicAdd(&S1a[(blockIdx.x & 15)*64 + tid], vA);
    }
}

// ---- imp layer3 BOTH chains in one launch (block-range split). ----
__global__ __launch_bounds__(256) void k_imp3_both(
    const float* __restrict__ XIe, const float* __restrict__ XIa,
    const double* __restrict__ S2e, const double* __restrict__ S2a,
    const float* __restrict__ W3e, const float* __restrict__ W3a,
    float* __restrict__ Ze, float* __restrict__ Za,
    double* __restrict__ S3e, double* __restrict__ S3a, double invRows)
{
    bool isA = (blockIdx.x >= (NEE/16));
    int blk = isA ? (blockIdx.x - NEE/16) : blockIdx.x;
    const float* XI = isA ? XIa : XIe;
    const double* S2 = isA ? S2a : S2e;
    const float* W3 = isA ? W3a : W3e;
    float* Z = isA ? Za : Ze;
    double* S3 = isA ? S3a : S3e;

    __shared__ float ss[64];
    __shared__ double red4[4];
    int tid = threadIdx.x; int grp = tid>>6, ch = tid&63;
    if (tid < 64) ss[tid] = qbn_s(S2, tid, invRows);
    __syncthreads();
    float s = ss[ch];
    double w3 = (double)W3[ch];
    double lr3 = 0.0;
#pragma unroll
    for (int i = 0; i < 4; ++i) {
        int ent = blk*16 + grp + 4*i;
        float x0 = XI[(size_t)ent*128+ch], x1 = XI[(size_t)ent*128+64+ch];
        float u0 = x0/s, u1 = x1/s;
        float mod = sqrtf(pair_m2(u0,u1));
        float cf = qcoef(mod);
        double v0 = (double)__fmul_rn(u0,cf) * w3;
        double v1 = (double)__fmul_rn(u1,cf) * w3;
#pragma unroll
        for (int m = 1; m < 64; m <<= 1) { v0 += __shfl_xor(v0,m,64); v1 += __shfl_xor(v1,m,64); }
        if (ch == 0) {
            float z0 = (float)v0, z1 = (float)v1;
            Z[(size_t)ent*2] = z0; Z[(size_t)ent*2+1] = z1;
            lr3 += (double)z0*z0 + (double)z1*z1;
        }
    }
    if (ch == 0) red4[grp] = lr3;
    __syncthreads();
    if (tid == 0) atomicAdd(&S3[(blk & 15)*8], red4[0]+red4[1]+red4[2]+red4[3]);
}

// ---- move_vec + oaq head + output cols 0..5. ----
__global__ __launch_bounds__(256) void k_final_small(
    const float* __restrict__ Zie, const float* __restrict__ Zia,
    const double* __restrict__ Sie3, const double* __restrict__ Sia3,
    const float* __restrict__ SFb,
    const float* __restrict__ Woa1, const float* __restrict__ boa1,
    const float* __restrict__ Woa2, const float* __restrict__ boa2,
    float* __restrict__ out, double invRows)
{
    __shared__ float sflds[4][64];
    int tid = threadIdx.x; int grp = tid>>6, ch = tid&63;
    int agent = blockIdx.x*4 + grp;
    float sie = sqrtf((float)(sum16sd8(Sie3)*invRows) + EPSF);
    float sia = sqrtf((float)(sum16sd8(Sia3)*invRows) + EPSF);
    double pv0 = 0.0, pv1 = 0.0;
    if (ch < NEN) {
        int ent = agent*NEN + ch;
        float z0 = Zie[(size_t)ent*2]/sie, z1 = Zie[(size_t)ent*2+1]/sie;
        float mod = sqrtf(pair_m2(z0,z1)); float cf = qcoef(mod);
        pv0 = (double)__fmul_rn(z0,cf); pv1 = (double)__fmul_rn(z1,cf);
        z0 = Zia[(size_t)ent*2]/sia; z1 = Zia[(size_t)ent*2+1]/sia;
        mod = sqrtf(pair_m2(z0,z1)); cf = qcoef(mod);
        pv0 += (double)__fmul_rn(z0,cf); pv1 += (double)__fmul_rn(z1,cf);
    }
#pragma unroll
    for (int m = 1; m < 64; m <<= 1) { pv0 += __shfl_xor(pv0,m,64); pv1 += __shfl_xor(pv1,m,64); }
    sflds[grp][ch] = SFb[(size_t)agent*64+ch];
    __syncthreads();
    double hd = (double)boa1[ch];
#pragma unroll
    for (int k = 0; k < 64; ++k) hd += (double)sflds[grp][k]*(double)Woa1[k*64+ch];
    float h = fmaxf((float)hd, 0.f);
    double q0 = (double)h*(double)Woa2[ch*3+0];
    double q1 = (double)h*(double)Woa2[ch*3+1];
    double q2 = (double)h*(double)Woa2[ch*3+2];
#pragma unroll
    for (int m = 1; m < 64; m <<= 1) { q0 += __shfl_xor(q0,m,64); q1 += __shfl_xor(q1,m,64); q2 += __shfl_xor(q2,m,64); }
    if (ch == 0) {
        float oaq0 = (float)(q0 + (double)boa2[0]);
        float oaq1 = (float)(q1 + (double)boa2[1]);
        float mmq  = (float)(q2 + (double)boa2[2]);
        float mv0 = (float)pv0, mv1 = (float)pv1;
        float* o = out + (size_t)agent*16;
        o[0] = oaq0; o[1] = oaq1;
        o[2] = mmq + mv1; o[3] = mmq - mv1;
        o[4] = mmq + mv0; o[5] = mmq - mv0;
    }
}

// ---- Attention MLP tail, R6: 32 rows/block, outer-product form.
//      Layer1: 4 j-cols x 4 rows/thread (float4 W1 + float4 escT per k).
//      Layer2: 4 j-cols x 2 rows/thread (float4 W2 + float2 h1T per k).
//      h2 aliased into escT (dead after layer1; barriers separate).
//      Per-output fmaf chains (init, then k ascending) bit-identical. ----
__global__ __launch_bounds__(256) void k_attn(
    const float* __restrict__ ATtop, const float* __restrict__ ESC,
    const float* __restrict__ W1,
    const float* __restrict__ W2, const float* __restrict__ b2,
    const float* __restrict__ W3, const float* __restrict__ b3,
    float* __restrict__ out)
{
    __shared__ __align__(16) float escT[64][36];   // [k][r], r=0..31
    __shared__ __align__(16) float h1T[128][36];   // [j][r]
    float (*h2)[68] = (float(*)[68])&escT[0][0];   // 32x68=2176 <= 64x36=2304
    int tid = threadIdx.x;
    int row0 = blockIdx.x*32;
#pragma unroll
    for (int i = 0; i < 8; ++i) {
        int idx = tid + i*256; int r = idx>>6; int j = idx&63;
        escT[j][r] = ESC[(size_t)(row0 + r)*64 + j];
    }
    __syncthreads();
    {   // layer1 bottom: j0 = 4*(tid&31), rr = tid>>5 -> rows rr*4..+3
        int j0 = (tid & 31)*4;
        int rr = tid >> 5;
        float acc[4][4];
#pragma unroll
        for (int ri = 0; ri < 4; ++ri) {
            int ent = row0 + rr*4 + ri; int agent = ent/NEN;
            float4 t = *(const float4*)&ATtop[(size_t)agent*128 + j0];
            acc[0][ri]=t.x; acc[1][ri]=t.y; acc[2][ri]=t.z; acc[3][ri]=t.w;
        }
#pragma unroll 4
        for (int k = 0; k < 64; ++k) {
            float4 w = *(const float4*)&W1[(size_t)(64+k)*128 + j0];
            float4 e = *(const float4*)&escT[k][rr*4];
            float wv[4] = {w.x,w.y,w.z,w.w};
            float ev[4] = {e.x,e.y,e.z,e.w};
#pragma unroll
            for (int ji = 0; ji < 4; ++ji)
#pragma unroll
                for (int ri = 0; ri < 4; ++ri)
                    acc[ji][ri] = fmaf(ev[ri], wv[ji], acc[ji][ri]);
        }
#pragma unroll
        for (int ji = 0; ji < 4; ++ji) {
            float4 o = make_float4(fmaxf(acc[ji][0],0.f), fmaxf(acc[ji][1],0.f),
                                   fmaxf(acc[ji][2],0.f), fmaxf(acc[ji][3],0.f));
            *(float4*)&h1T[j0+ji][rr*4] = o;
        }
    }
    __syncthreads();
    {   // layer2: j20 = 4*(tid&15), rr2 = tid>>4 -> rows rr2*2..+1
        int j20 = (tid & 15)*4;
        int rr2 = tid >> 4;
        float acc[4][2];
#pragma unroll
        for (int ji = 0; ji < 4; ++ji) {
            float bb = b2[j20+ji];
            acc[ji][0] = bb; acc[ji][1] = bb;
        }
#pragma unroll 8
        for (int k = 0; k < 128; ++k) {
            float4 w = *(const float4*)&W2[(size_t)k*64 + j20];
            float2 p = *(const float2*)&h1T[k][rr2*2];
            float wv[4] = {w.x,w.y,w.z,w.w};
#pragma unroll
            for (int ji = 0; ji < 4; ++ji) {
                acc[ji][0] = fmaf(p.x, wv[ji], acc[ji][0]);
                acc[ji][1] = fmaf(p.y, wv[ji], acc[ji][1]);
            }
        }
#pragma unroll
        for (int ji = 0; ji < 4; ++ji) {
            h2[rr2*2+0][j20+ji] = fmaxf(acc[ji][0], 0.f);
            h2[rr2*2+1][j20+ji] = fmaxf(acc[ji][1], 0.f);
        }
    }
    __syncthreads();
    {   // layer3: two halves of 16 rows; exact 16-lane structure preserved
#pragma unroll
        for (int half = 0; half < 2; ++half) {
            int r3 = (tid >> 4) + half*16, l3 = tid & 15;
            float s = 0.f;
#pragma unroll
            for (int q = 0; q < 4; ++q) s = fmaf(h2[r3][l3 + 16*q], W3[l3 + 16*q], s);
#pragma unroll
            for (int m = 1; m < 16; m <<= 1) s += __shfl_xor(s, m, 64);
            if (l3 == 0) {
                int ent = row0 + r3; int agent = ent/NEN; int e = ent%NEN;
                out[(size_t)agent*16 + 6 + e] = s + b3[0];
            }
        }
    }
}

extern "C" void kernel_launch(void* const* d_in, const int* in_sizes, int n_in,
                              void* d_out, int out_size, void* d_ws, size_t ws_size,
                              hipStream_t stream) {
    const float* own  = (const float*)d_in[0];
    const float* ef   = (const float*)d_in[1];
    const float* af   = (const float*)d_in[2];
    const float* W_e1 = (const float*)d_in[3];
    const float* W_e2 = (const float*)d_in[4];
    const float* W_a1 = (const float*)d_in[5];
    const float* W_a2 = (const float*)d_in[6];
    const float* W_f1 = (const float*)d_in[7];
    const float* W_f2 = (const float*)d_in[8];
    const float* W_ie1= (const float*)d_in[9];
    const float* W_ie2= (const float*)d_in[10];
    const float* W_ie3= (const float*)d_in[11];
    const float* W_ia1= (const float*)d_in[12];
    const float* W_ia2= (const float*)d_in[13];
    const float* W_ia3= (const float*)d_in[14];
    const float* W_oa1= (const float*)d_in[15];
    const float* b_oa1= (const float*)d_in[16];
    const float* W_oa2= (const float*)d_in[17];
    const float* b_oa2= (const float*)d_in[18];
    const float* W_at1= (const float*)d_in[19];
    const float* b_at1= (const float*)d_in[20];
    const float* W_at2= (const float*)d_in[21];
    const float* b_at2= (const float*)d_in[22];
    const float* W_at3= (const float*)d_in[23];
    const float* b_at3= (const float*)d_in[24];
    float* out = (float*)d_out;
    float* wsf = (float*)d_ws;
    double* Sd = (double*)d_ws;

    size_t o = (size_t)NDOUBLES*2;
    float*  X_E  = wsf + o; o += (size_t)NEE*128;  // becomes XI_A after k_imp1_both
    float*  X_A  = wsf + o; o += (size_t)NAE*128;
    float*  F1   = wsf + o; o += (size_t)NAG*128;  // becomes ATtop after k_vf_vtop
    float*  SFb  = wsf + o; o += (size_t)NAG*64;
    float*  VT_IE = wsf + o; o += (size_t)NAG*128;
    float*  VT_IA = wsf + o; o += (size_t)NAG*128;
    float*  XI   = wsf + o; o += (size_t)NEE*128;  // XI_E
    float*  Z_IE = wsf + o; o += (size_t)NEE*2;
    float*  Z_IA = wsf + o; o += (size_t)NEE*2;
    float*  ESC  = wsf + o; o += (size_t)NEE*64;   // e_scalar (pair_m2 of X_E)

    double* S_E1 = Sd + DOFF_SE1;  double* S_E2 = Sd + DOFF_SE2;
    double* S_A1 = Sd + DOFF_SA1;  double* S_A2 = Sd + DOFF_SA2;
    double* S_F1 = Sd + DOFF_SF1;  double* S_F2 = Sd + DOFF_SF2;
    double* S_IE1= Sd + DOFF_SIE1; double* S_IE2= Sd + DOFF_SIE2;
    double* S_IA1= Sd + DOFF_SIA1; double* S_IA2= Sd + DOFF_SIA2;
    double* S_IE3= Sd + DOFF_SIE3; double* S_IA3= Sd + DOFF_SIA3;

    const double invRe = 1.0/(double)(NEE*2);
    const double invRa = 1.0/(double)(NAE*2);
    const double invRf = 1.0/(double)(NAG*2);

    hipMemsetAsync(Sd, 0, (size_t)NDOUBLES*sizeof(double), stream);

    k_build_both<<<NBLK_BE + NBLK_BA, 256, 0, stream>>>(
        ef, af, own, W_e1, W_a1, X_E, X_A, S_E1, S_A1);
    k_pair_both<<<NBLK_PE64 + NBLK_PA64, 512, 0, stream>>>(
        X_E, S_E1, S_E2, W_e2, invRe, X_A, S_A1, S_A2, W_a2, invRa);
    k_finalize_pair<<<NEE*32/256, 256, 0, stream>>>(X_E, S_E2, invRe, ESC);
    k_pool_f1<<<NAG/4, 256, 0, stream>>>(X_E, X_A, S_A2, invRa, W_f1, F1, S_F1);
    k_pair_layer<<<NAG/64, 512, 0, stream>>>(F1, S_F1, S_F2, W_f2, invRf);
    k_vf_vtop<<<NAG/4, 256, 0, stream>>>(F1, S_F2, SFb, W_ie1, W_ia1,
                                         W_at1, b_at1, VT_IE, VT_IA, invRf);
    // both importance chains fused: XI_E -> XI, XI_A -> X_E (in place)
    k_imp1_both<<<NEE/32, 512, 0, stream>>>(X_E, VT_IE, VT_IA, W_ie1, W_ia1,
                                            XI, S_IE1, S_IA1);
    k_pair_both<<<NBLK_PE64 + NBLK_PE64, 512, 0, stream>>>(
        XI, S_IE1, S_IE2, W_ie2, invRe, X_E, S_IA1, S_IA2, W_ia2, invRe);
    k_imp3_both<<<2*(NEE/16), 256, 0, stream>>>(XI, X_E, S_IE2, S_IA2,
                                                W_ie3, W_ia3, Z_IE, Z_IA,
                                                S_IE3, S_IA3, invRe);

    k_final_small<<<NAG/4, 256, 0, stream>>>(Z_IE, Z_IA, S_IE3, S_IA3, SFb,
                                             W_oa1, b_oa1, W_oa2, b_oa2, out, invRe);
    k_attn<<<NEE/32, 256, 0, stream>>>(F1, ESC, W_at1, W_at2, b_at2,
                                       W_at3, b_at3, out);
}

// Round 8
// 557.627 us; speedup vs baseline: 1.0610x; 1.0610x over previous
//
#include <hip/hip_runtime.h>
#include <math.h>

// Problem constants
#define BATCH 1024
#define NA 10
#define NEN 10
#define NALY 9
#define NAG (BATCH*NA)          // 10240
#define NEE (NAG*NEN)           // 102400
#define NAE (NAG*NALY)          // 92160
#define EPSF 1e-5f

// f64 replicated qbn-sum buffers (16 replicas), at start of ws (double units)
#define DOFF_SE1 0
#define DOFF_SE2 1024
#define DOFF_SA1 2048
#define DOFF_SA2 3072
#define DOFF_SF1 4096
#define DOFF_SF2 5120
#define DOFF_SIE1 6144
#define DOFF_SIE2 7168
#define DOFF_SIA1 8192
#define DOFF_SIA2 9216
#define DOFF_SIE3 10240   // 16 replicas x stride 8
#define DOFF_SIA3 10368
#define NDOUBLES 16384

#define NBLK_BE (NEE/8)    // 12800
#define NBLK_BA (NAE/8)    // 11520
#define NBLK_PE64 (NEE/64) // 1600
#define NBLK_PA64 (NAE/64) // 1440

__device__ __forceinline__ double sum16vd(const double* __restrict__ S, int ch) {
    double s = 0.0;
#pragma unroll
    for (int r = 0; r < 16; ++r) s += S[r*64 + ch];
    return s;
}
__device__ __forceinline__ double sum16sd8(const double* __restrict__ S) {
    double s = 0.0;
#pragma unroll
    for (int r = 0; r < 16; ++r) s += S[r*8];
    return s;
}
__device__ __forceinline__ float qbn_s(const double* __restrict__ S, int ch, double invRows) {
    float m = (float)(sum16vd(S, ch)*invRows);
    return sqrtf(m + EPSF);
}
__device__ __forceinline__ void red_to_S(const double* red, double* S, int bid, int tid) {
    if (tid < 64) {
        double v = red[tid] + red[tid+64] + red[tid+128] + red[tid+192];
        atomicAdd(&S[(bid & 15)*64 + tid], v);
    }
}
// np-lattice pair mod^2: fl(fl(x0^2)+fl(x1^2)) (no FMA contraction)
__device__ __forceinline__ float pair_m2(float x0, float x1) {
    return __fadd_rn(__fmul_rn(x0,x0), __fmul_rn(x1,x1));
}
// qrelu coeff: bit-identical to mod/fmaxf(1,mod) for finite mod:
//   mod<=1 -> mod/1 == mod exactly; mod>1 -> mod/mod == 1.0f exactly.
__device__ __forceinline__ float qcoef(float mod) {
    return fminf(mod, 1.0f);
}

// ---- build_vec + layer1 GEMM, E and A fused in one launch.
//      Per-output FP sequence identical (REVERSED k, FROZEN). ----
__global__ __launch_bounds__(256) void k_build_both(
    const float* __restrict__ ef, const float* __restrict__ af,
    const float* __restrict__ own,
    const float* __restrict__ We1, const float* __restrict__ Wa1,
    float* __restrict__ XE, float* __restrict__ XA,
    double* __restrict__ SE1, double* __restrict__ SA1)
{
    bool isA = (blockIdx.x >= NBLK_BE);
    int blk = isA ? (blockIdx.x - NBLK_BE) : blockIdx.x;
    const float* feats = isA ? af : ef;
    const float* W1    = isA ? Wa1 : We1;
    float* X           = isA ? XA : XE;
    double* S1         = isA ? SA1 : SE1;
    int nEntPerAgent   = isA ? NALY : NEN;

    __shared__ float wlds[19*64];
    __shared__ float gpc[16][19];     // (el*2+c, k): pc * g  precomputed
    __shared__ double red[256];
    int tid = threadIdx.x;
    for (int i = tid; i < 19*64; i += 256) wlds[i] = W1[i];
    if (tid < 152) {
        int el = tid / 19, chg = tid % 19;
        int ent = blk*8 + el;
        const float* f = feats + (size_t)ent*9;
        int agent = ent / nEntPerAgent;
        float px = f[2], py = f[3];
        float pm = sqrtf(__fadd_rn(__fmul_rn(px,px), __fmul_rn(py,py)));
        float val;
        if (chg == 0) val = 1.f;
        else if (chg < 8) {
            int j = chg - 1;
            int fi = (j < 2) ? j : (j + 2);
            float o = f[fi];
            float om = sqrtf(__fmul_rn(__fmul_rn(2.0f,o),o));
            val = (pm == 0.f) ? 0.f : __fdiv_rn(om, pm);
        } else {
            float o = own[(size_t)agent*11 + (chg-8)];
            float t = __fmul_rn(o,o);
            float om = sqrtf(__fadd_rn(t,t));
            val = (pm == 0.f) ? 0.f : __fdiv_rn(om, pm);
        }
        // same bits as the old per-lane __fmul_rn(pc, g[el][k])
        gpc[el*2 + 0][chg] = __fmul_rn(px, val);
        gpc[el*2 + 1][chg] = __fmul_rn(py, val);
    }
    __syncthreads();
    int l = tid >> 7, c = (tid >> 6) & 1, ch = tid & 63;
    float wreg[19];
#pragma unroll
    for (int k = 0; k < 19; ++k) wreg[k] = wlds[k*64+ch];
    double lr = 0.0;
#pragma unroll
    for (int i = 0; i < 4; ++i) {
        int el = l + 2*i;
        int ent = blk*8 + el;
        int row = el*2 + c;
        float acc = 0.f;
#pragma unroll
        for (int k = 18; k >= 0; --k) {            // REVERSED k (frozen)
            acc = fmaf(gpc[row][k], wreg[k], acc);
        }
        X[(size_t)ent*128 + c*64 + ch] = acc;
        lr += (double)acc * (double)acc;
    }
    red[tid] = lr;
    __syncthreads();
    red_to_S(red, S1, blk, tid);
}

// ---- pair-layer core: 512 threads, 64 rows/block, 2 rows/thread.
//      dredw aliased into ybuf (barrier after GEMM makes it race-free).
//      Each output's fmaf chain (REVERSED k) is unchanged bit-for-bit. ----
__device__ __forceinline__ void pair_layer_body(
    float* __restrict__ X, const double* __restrict__ Sin, double* __restrict__ Sout,
    const float* __restrict__ W, double invRows, int blk)
{
    __shared__ float wlds[4096];
    __shared__ __align__(16) float ybuf[64][132];
    __shared__ float ss[64];
    double* dredw = (double*)&ybuf[0][0];   // 8 waves x 64 ch = 4 KB, aliased
    int tid = threadIdx.x;
    for (int i = tid; i < 4096; i += 512) wlds[i] = W[i];
    if (tid < 64) ss[tid] = qbn_s(Sin, tid, invRows);
    __syncthreads();
    int rl = tid >> 4;                 // 0..31
    int ch0 = (tid & 15) * 4;
#pragma unroll
    for (int h = 0; h < 2; ++h) {
        int r = rl + h*32;
        size_t row = (size_t)blk*64 + r;
        float4 xv0 = *(const float4*)&X[row*128 + ch0];
        float4 xv1 = *(const float4*)&X[row*128 + 64 + ch0];
        float xs0[4] = {xv0.x,xv0.y,xv0.z,xv0.w};
        float xs1[4] = {xv1.x,xv1.y,xv1.z,xv1.w};
        float y0[4], y1[4];
#pragma unroll
        for (int i = 0; i < 4; ++i) {
            float s = ss[ch0+i];
            float u0 = xs0[i]/s, u1 = xs1[i]/s;
            float mod = sqrtf(pair_m2(u0,u1));
            float cf = qcoef(mod);
            y0[i] = __fmul_rn(u0,cf);
            y1[i] = __fmul_rn(u1,cf);
        }
        *(float4*)&ybuf[r][2*ch0]     = make_float4(y0[0],y1[0],y0[1],y1[1]);
        *(float4*)&ybuf[r][2*ch0 + 4] = make_float4(y0[2],y1[2],y0[3],y1[3]);
    }
    __syncthreads();
    float a0[4] = {0.f,0.f,0.f,0.f};
    float a1[4] = {0.f,0.f,0.f,0.f};
    float c0[4] = {0.f,0.f,0.f,0.f};
    float c1[4] = {0.f,0.f,0.f,0.f};
#pragma unroll
    for (int k = 63; k >= 1; k -= 2) {           // REVERSED k (frozen)
        float4 wk  = *(const float4*)&wlds[k*64 + ch0];
        float4 wk1 = *(const float4*)&wlds[(k-1)*64 + ch0];
        float4 ya  = *(const float4*)&ybuf[rl][2*k - 2];
        float4 yb  = *(const float4*)&ybuf[rl+32][2*k - 2];
        float wkv[4]  = {wk.x,wk.y,wk.z,wk.w};
        float wk1v[4] = {wk1.x,wk1.y,wk1.z,wk1.w};
#pragma unroll
        for (int i = 0; i < 4; ++i) {
            a0[i] = fmaf(ya.z, wkv[i], a0[i]);
            a1[i] = fmaf(ya.w, wkv[i], a1[i]);
        }
#pragma unroll
        for (int i = 0; i < 4; ++i) {
            a0[i] = fmaf(ya.x, wk1v[i], a0[i]);
            a1[i] = fmaf(ya.y, wk1v[i], a1[i]);
        }
#pragma unroll
        for (int i = 0; i < 4; ++i) {
            c0[i] = fmaf(yb.z, wkv[i], c0[i]);
            c1[i] = fmaf(yb.w, wkv[i], c1[i]);
        }
#pragma unroll
        for (int i = 0; i < 4; ++i) {
            c0[i] = fmaf(yb.x, wk1v[i], c0[i]);
            c1[i] = fmaf(yb.y, wk1v[i], c1[i]);
        }
    }
    size_t rowA = (size_t)blk*64 + rl;
    size_t rowB = rowA + 32;
    *(float4*)&X[rowA*128 + ch0]      = make_float4(a0[0],a0[1],a0[2],a0[3]);
    *(float4*)&X[rowA*128 + 64 + ch0] = make_float4(a1[0],a1[1],a1[2],a1[3]);
    *(float4*)&X[rowB*128 + ch0]      = make_float4(c0[0],c0[1],c0[2],c0[3]);
    *(float4*)&X[rowB*128 + 64 + ch0] = make_float4(c1[0],c1[1],c1[2],c1[3]);
    __syncthreads();   // ybuf reads done; safe to reuse as dredw
    {
        int wv = tid >> 6;             // 0..7
#pragma unroll
        for (int i = 0; i < 4; ++i) {
            double d = (double)a0[i]*a0[i] + (double)a1[i]*a1[i]
                     + (double)c0[i]*c0[i] + (double)c1[i]*c1[i];
            d += __shfl_xor(d, 16, 64);
            d += __shfl_xor(d, 32, 64);
            if ((tid & 48) == 0) dredw[wv*64 + ch0+i] = d;
        }
    }
    __syncthreads();
    if (tid < 64) {
        double v = 0.0;
#pragma unroll
        for (int w = 0; w < 8; ++w) v += dredw[w*64 + tid];
        atomicAdd(&Sout[(blk & 15)*64 + tid], v);
    }
}

// ---- pair layer for two X-streams in one launch (split at NBLK_PE64). ----
__global__ __launch_bounds__(512) void k_pair_both(
    float* __restrict__ XE, const double* __restrict__ SE1, double* __restrict__ SE2,
    const float* __restrict__ We2, double invRe,
    float* __restrict__ XA, const double* __restrict__ SA1, double* __restrict__ SA2,
    const float* __restrict__ Wa2, double invRa)
{
    if (blockIdx.x < NBLK_PE64)
        pair_layer_body(XE, SE1, SE2, We2, invRe, blockIdx.x);
    else
        pair_layer_body(XA, SA1, SA2, Wa2, invRa, blockIdx.x - NBLK_PE64);
}

// ---- generic pair layer (F1). ----
__global__ __launch_bounds__(512) void k_pair_layer(
    float* __restrict__ X, const double* __restrict__ Sin, double* __restrict__ Sout,
    const float* __restrict__ W, double invRows)
{
    pair_layer_body(X, Sin, Sout, W, invRows, blockIdx.x);
}

// ---- Finalize (E only): y = qrelu(qbn(x)) in place + ESC = pair_m2. ----
__global__ __launch_bounds__(256) void k_finalize_pair(
    float* __restrict__ X, const double* __restrict__ S2, double invRows,
    float* __restrict__ ESC)
{
    __shared__ float ss[64];
    if (threadIdx.x < 64) ss[threadIdx.x] = qbn_s(S2, threadIdx.x, invRows);
    int t = blockIdx.x*256 + threadIdx.x;
    int rl = t >> 4;              // (ent*2 + c) row index
    int ch0 = (t & 15) * 4;
    size_t base    = (size_t)rl*64 + ch0;
    size_t partner = (size_t)(rl ^ 1)*64 + ch0;
    float4 xv  = *(const float4*)&X[base];
    float4 xov = *(const float4*)&X[partner];
    __syncthreads();
    float xs[4]  = {xv.x,xv.y,xv.z,xv.w};
    float xos[4] = {xov.x,xov.y,xov.z,xov.w};
    float r[4], esc[4];
    int c = rl & 1;
#pragma unroll
    for (int i = 0; i < 4; ++i) {
        float s = ss[ch0+i];
        float u  = xs[i]/s;
        float uo = xos[i]/s;
        float u0 = (c==0) ? u : uo, u1 = (c==0) ? uo : u;
        float mod = sqrtf(pair_m2(u0,u1));
        float cf = qcoef(mod);
        r[i] = __fmul_rn(u, cf);
        if (c == 0) {
            float y1v = __fmul_rn(uo, cf);   // identical bits to partner's write
            esc[i] = pair_m2(r[i], y1v);
        }
    }
    *(float4*)&X[base] = make_float4(r[0],r[1],r[2],r[3]);
    if (c == 0) {
        int ent = rl >> 1;
        *(float4*)&ESC[(size_t)ent*64 + ch0] = make_float4(esc[0],esc[1],esc[2],esc[3]);
    }
}

// ---- Pool + f1 GEMM, ally finalize fused (identical op sequence). ----
__global__ __launch_bounds__(256) void k_pool_f1(
    const float* __restrict__ XE, const float* __restrict__ XAraw,
    const double* __restrict__ SA2, double invRa,
    const float* __restrict__ Wf1, float* __restrict__ F1, double* __restrict__ Sf1)
{
    __shared__ float wlds[4096];
    __shared__ float v[4][2][64];
    __shared__ float ssa[64];
    __shared__ double red[256];
    int tid = threadIdx.x;
    for (int i = tid; i < 4096; i += 256) wlds[i] = Wf1[i];
    if (tid < 64) ssa[tid] = qbn_s(SA2, tid, invRa);
    __syncthreads();
    int grp = tid>>6, ch = tid&63;
    int agent = blockIdx.x*4 + grp;
    float best = -1.f, v0 = 0.f, v1 = 0.f;
    for (int e = 0; e < NEN; ++e) {
        size_t b = (size_t)(agent*NEN+e)*128;
        float x0 = XE[b+ch], x1 = XE[b+64+ch];
        float m2 = pair_m2(x0,x1);
        if (m2 > best) { best = m2; v0 = x0; v1 = x1; }
    }
    float sa = ssa[ch];
    for (int l = 0; l < NALY; ++l) {
        size_t b = (size_t)(agent*NALY+l)*128;
        float r0 = XAraw[b+ch], r1 = XAraw[b+64+ch];
        float u0 = r0/sa, u1 = r1/sa;
        float modf = sqrtf(pair_m2(u0,u1));
        float cff = qcoef(modf);
        float x0 = __fmul_rn(u0,cff), x1 = __fmul_rn(u1,cff);
        float m2 = pair_m2(x0,x1);
        if (m2 > best) { best = m2; v0 = x0; v1 = x1; }
    }
    v[grp][0][ch] = v0; v[grp][1][ch] = v1;
    __syncthreads();
    float a0 = 0.f, a1 = 0.f;
#pragma unroll
    for (int k = 0; k < 64; ++k) {
        float w = wlds[k*64+ch];
        a0 = fmaf(v[grp][0][k], w, a0);
        a1 = fmaf(v[grp][1][k], w, a1);
    }
    F1[(size_t)agent*128+ch] = a0; F1[(size_t)agent*128+64+ch] = a1;
    red[tid] = (double)a0*a0 + (double)a1*a1;
    __syncthreads();
    red_to_S(red, Sf1, blockIdx.x, tid);
}

// ---- vf finalize + SFb + VT = vf @ W1top for both imp chains
//      + ATtop = b_at1 + sf @ W_at1[0:64] (hoisted attn layer1 top half).
//      ATtop overwrites F1 in place (dead after; reads precede barrier). ----
__global__ __launch_bounds__(256) void k_vf_vtop(
    float* __restrict__ F1, const double* __restrict__ Sf2,
    float* __restrict__ SFb,
    const float* __restrict__ Wie1, const float* __restrict__ Wia1,
    const float* __restrict__ Wat1, const float* __restrict__ bat1,
    float* __restrict__ VTie, float* __restrict__ VTia, double invRows)
{
    __shared__ float wie[4096];
    __shared__ float wia[4096];
    __shared__ float vf[4][2][64];
    __shared__ float sfv[4][64];
    int tid = threadIdx.x;
    for (int i = tid; i < 4096; i += 256) { wie[i] = Wie1[i]; wia[i] = Wia1[i]; }
    int grp = tid>>6, ch = tid&63;
    int agent = blockIdx.x*4 + grp;
    float x0 = F1[(size_t)agent*128+ch], x1 = F1[(size_t)agent*128+64+ch];
    float s = qbn_s(Sf2, ch, invRows);
    float u0 = x0/s, u1 = x1/s;
    float mod = sqrtf(pair_m2(u0,u1));
    float cf = qcoef(mod);
    float y0 = __fmul_rn(u0,cf), y1 = __fmul_rn(u1,cf);
    vf[grp][0][ch] = y0; vf[grp][1][ch] = y1;
    float sf = pair_m2(y0,y1);
    SFb[(size_t)agent*64+ch] = sf;
    sfv[grp][ch] = sf;
    __syncthreads();
    float a0=0.f,a1=0.f,b0=0.f,b1=0.f;
    float at0 = bat1[ch], at1 = bat1[64+ch];
#pragma unroll
    for (int k = 0; k < 64; ++k) {
        float f0 = vf[grp][0][k], f1 = vf[grp][1][k];
        a0 = fmaf(f0, wie[k*64+ch], a0); a1 = fmaf(f1, wie[k*64+ch], a1);
        b0 = fmaf(f0, wia[k*64+ch], b0); b1 = fmaf(f1, wia[k*64+ch], b1);
        float sv = sfv[grp][k];
        at0 = fmaf(sv, Wat1[k*128 + ch], at0);
        at1 = fmaf(sv, Wat1[k*128 + 64 + ch], at1);
    }
    VTie[(size_t)agent*128+ch] = a0; VTie[(size_t)agent*128+64+ch] = a1;
    VTia[(size_t)agent*128+ch] = b0; VTia[(size_t)agent*128+64+ch] = b1;
    F1[(size_t)agent*128+ch] = at0; F1[(size_t)agent*128+64+ch] = at1;
}

// ---- imp layer1 BOTH chains: 512 threads, 32 ents/block, 2 rows/thread.
//      dredw aliased into xt (barrier after GEMM). Per-output chains frozen. ----
__global__ __launch_bounds__(512) void k_imp1_both(
    float* __restrict__ XE,
    const float* __restrict__ VTe, const float* __restrict__ VTa,
    const float* __restrict__ W1e, const float* __restrict__ W1a,
    float* __restrict__ XIe,
    double* __restrict__ S1e, double* __restrict__ S1a)
{
    __shared__ float wldsE[4096];
    __shared__ float wldsA[4096];
    __shared__ __align__(16) float xt[64][68];
    double* dredwE = (double*)&xt[0][0];        // 8 waves x 64 ch
    double* dredwA = dredwE + 512;              // next 4 KB
    int tid = threadIdx.x;
    for (int i = tid; i < 4096; i += 512) { wldsE[i] = W1e[4096 + i]; wldsA[i] = W1a[4096 + i]; }
#pragma unroll
    for (int i = 0; i < 2; ++i) {
        int fidx = tid + i*512;               // float4 index 0..1023
        int r = fidx >> 4;                    // row 0..63 (= ent_local*2 + c)
        int kq = (fidx & 15) * 4;
        float4 t4 = *(const float4*)&XE[(size_t)blockIdx.x*4096 + (size_t)fidx*4];
        *(float4*)&xt[r][kq] = t4;
    }
    __syncthreads();
    int rl = tid >> 4;                        // 0..31
    int ch0 = (tid & 15) * 4;
    int entA = blockIdx.x*32 + (rl >> 1);     // rows rl      -> ents 0..15
    int entB = entA + 16;                     // rows rl+32   -> ents 16..31
    int c = rl & 1;
    int agentA = entA / NEN, agentB = entB / NEN;
    float4 vteA = *(const float4*)&VTe[(size_t)agentA*128 + c*64 + ch0];
    float4 vtaA = *(const float4*)&VTa[(size_t)agentA*128 + c*64 + ch0];
    float4 vteB = *(const float4*)&VTe[(size_t)agentB*128 + c*64 + ch0];
    float4 vtaB = *(const float4*)&VTa[(size_t)agentB*128 + c*64 + ch0];
    float accEA[4] = {vteA.x, vteA.y, vteA.z, vteA.w};
    float accAA[4] = {vtaA.x, vtaA.y, vtaA.z, vtaA.w};
    float accEB[4] = {vteB.x, vteB.y, vteB.z, vteB.w};
    float accAB[4] = {vtaB.x, vtaB.y, vtaB.z, vtaB.w};
#pragma unroll
    for (int k = 0; k < 64; k += 4) {
        float4 xa4 = *(const float4*)&xt[rl][k];
        float4 xb4 = *(const float4*)&xt[rl+32][k];
        float xa[4] = {xa4.x, xa4.y, xa4.z, xa4.w};
        float xb[4] = {xb4.x, xb4.y, xb4.z, xb4.w};
#pragma unroll
        for (int kk = 0; kk < 4; ++kk) {
            float4 we = *(const float4*)&wldsE[(k+kk)*64 + ch0];
            accEA[0] = fmaf(xa[kk], we.x, accEA[0]);
            accEA[1] = fmaf(xa[kk], we.y, accEA[1]);
            accEA[2] = fmaf(xa[kk], we.z, accEA[2]);
            accEA[3] = fmaf(xa[kk], we.w, accEA[3]);
            accEB[0] = fmaf(xb[kk], we.x, accEB[0]);
            accEB[1] = fmaf(xb[kk], we.y, accEB[1]);
            accEB[2] = fmaf(xb[kk], we.z, accEB[2]);
            accEB[3] = fmaf(xb[kk], we.w, accEB[3]);
            float4 wa = *(const float4*)&wldsA[(k+kk)*64 + ch0];
            accAA[0] = fmaf(xa[kk], wa.x, accAA[0]);
            accAA[1] = fmaf(xa[kk], wa.y, accAA[1]);
            accAA[2] = fmaf(xa[kk], wa.z, accAA[2]);
            accAA[3] = fmaf(xa[kk], wa.w, accAA[3]);
            accAB[0] = fmaf(xb[kk], wa.x, accAB[0]);
            accAB[1] = fmaf(xb[kk], wa.y, accAB[1]);
            accAB[2] = fmaf(xb[kk], wa.z, accAB[2]);
            accAB[3] = fmaf(xb[kk], wa.w, accAB[3]);
        }
    }
    *(float4*)&XIe[(size_t)entA*128 + c*64 + ch0] = make_float4(accEA[0],accEA[1],accEA[2],accEA[3]);
    *(float4*)&XIe[(size_t)entB*128 + c*64 + ch0] = make_float4(accEB[0],accEB[1],accEB[2],accEB[3]);
    *(float4*)&XE [(size_t)entA*128 + c*64 + ch0] = make_float4(accAA[0],accAA[1],accAA[2],accAA[3]);
    *(float4*)&XE [(size_t)entB*128 + c*64 + ch0] = make_float4(accAB[0],accAB[1],accAB[2],accAB[3]);
    __syncthreads();   // xt reads done; safe to reuse as dredw
    int wv = tid >> 6;
#pragma unroll
    for (int i = 0; i < 4; ++i) {
        double dE = (double)accEA[i]*accEA[i] + (double)accEB[i]*accEB[i];
        dE += __shfl_xor(dE, 16, 64);
        dE += __shfl_xor(dE, 32, 64);
        double dA = (double)accAA[i]*accAA[i] + (double)accAB[i]*accAB[i];
        dA += __shfl_xor(dA, 16, 64);
        dA += __shfl_xor(dA, 32, 64);
        if ((tid & 48) == 0) {
            dredwE[wv*64 + ch0+i] = dE;
            dredwA[wv*64 + ch0+i] = dA;
        }
    }
    __syncthreads();
    if (tid < 64) {
        double vE = 0.0, vA = 0.0;
#pragma unroll
        for (int w = 0; w < 8; ++w) { vE += dredwE[w*64 + tid]; vA += dredwA[w*64 + tid]; }
        atomicAdd(&S1e[(blockIdx.x & 15)*64 + tid], vE);
        atomicAdd(&S1a[(blockIdx.x & 15)*64 + tid], vA);
    }
}

// ---- imp layer3 BOTH chains in one launch (block-range split). ----
__global__ __launch_bounds__(256) void k_imp3_both(
    const float* __restrict__ XIe, const float* __restrict__ XIa,
    const double* __restrict__ S2e, const double* __restrict__ S2a,
    const float* __restrict__ W3e, const float* __restrict__ W3a,
    float* __restrict__ Ze, float* __restrict__ Za,
    double* __restrict__ S3e, double* __restrict__ S3a, double invRows)
{
    bool isA = (blockIdx.x >= (NEE/16));
    int blk = isA ? (blockIdx.x - NEE/16) : blockIdx.x;
    const float* XI = isA ? XIa : XIe;
    const double* S2 = isA ? S2a : S2e;
    const float* W3 = isA ? W3a : W3e;
    float* Z = isA ? Za : Ze;
    double* S3 = isA ? S3a : S3e;

    __shared__ float ss[64];
    __shared__ double red4[4];
    int tid = threadIdx.x; int grp = tid>>6, ch = tid&63;
    if (tid < 64) ss[tid] = qbn_s(S2, tid, invRows);
    __syncthreads();
    float s = ss[ch];
    double w3 = (double)W3[ch];
    double lr3 = 0.0;
#pragma unroll
    for (int i = 0; i < 4; ++i) {
        int ent = blk*16 + grp + 4*i;
        float x0 = XI[(size_t)ent*128+ch], x1 = XI[(size_t)ent*128+64+ch];
        float u0 = x0/s, u1 = x1/s;
        float mod = sqrtf(pair_m2(u0,u1));
        float cf = qcoef(mod);
        double v0 = (double)__fmul_rn(u0,cf) * w3;
        double v1 = (double)__fmul_rn(u1,cf) * w3;
#pragma unroll
        for (int m = 1; m < 64; m <<= 1) { v0 += __shfl_xor(v0,m,64); v1 += __shfl_xor(v1,m,64); }
        if (ch == 0) {
            float z0 = (float)v0, z1 = (float)v1;
            Z[(size_t)ent*2] = z0; Z[(size_t)ent*2+1] = z1;
            lr3 += (double)z0*z0 + (double)z1*z1;
        }
    }
    if (ch == 0) red4[grp] = lr3;
    __syncthreads();
    if (tid == 0) atomicAdd(&S3[(blk & 15)*8], red4[0]+red4[1]+red4[2]+red4[3]);
}

// ---- move_vec + oaq head + output cols 0..5. ----
__global__ __launch_bounds__(256) void k_final_small(
    const float* __restrict__ Zie, const float* __restrict__ Zia,
    const double* __restrict__ Sie3, const double* __restrict__ Sia3,
    const float* __restrict__ SFb,
    const float* __restrict__ Woa1, const float* __restrict__ boa1,
    const float* __restrict__ Woa2, const float* __restrict__ boa2,
    float* __restrict__ out, double invRows)
{
    __shared__ float sflds[4][64];
    int tid = threadIdx.x; int grp = tid>>6, ch = tid&63;
    int agent = blockIdx.x*4 + grp;
    float sie = sqrtf((float)(sum16sd8(Sie3)*invRows) + EPSF);
    float sia = sqrtf((float)(sum16sd8(Sia3)*invRows) + EPSF);
    double pv0 = 0.0, pv1 = 0.0;
    if (ch < NEN) {
        int ent = agent*NEN + ch;
        float z0 = Zie[(size_t)ent*2]/sie, z1 = Zie[(size_t)ent*2+1]/sie;
        float mod = sqrtf(pair_m2(z0,z1)); float cf = qcoef(mod);
        pv0 = (double)__fmul_rn(z0,cf); pv1 = (double)__fmul_rn(z1,cf);
        z0 = Zia[(size_t)ent*2]/sia; z1 = Zia[(size_t)ent*2+1]/sia;
        mod = sqrtf(pair_m2(z0,z1)); cf = qcoef(mod);
        pv0 += (double)__fmul_rn(z0,cf); pv1 += (double)__fmul_rn(z1,cf);
    }
#pragma unroll
    for (int m = 1; m < 64; m <<= 1) { pv0 += __shfl_xor(pv0,m,64); pv1 += __shfl_xor(pv1,m,64); }
    sflds[grp][ch] = SFb[(size_t)agent*64+ch];
    __syncthreads();
    double hd = (double)boa1[ch];
#pragma unroll
    for (int k = 0; k < 64; ++k) hd += (double)sflds[grp][k]*(double)Woa1[k*64+ch];
    float h = fmaxf((float)hd, 0.f);
    double q0 = (double)h*(double)Woa2[ch*3+0];
    double q1 = (double)h*(double)Woa2[ch*3+1];
    double q2 = (double)h*(double)Woa2[ch*3+2];
#pragma unroll
    for (int m = 1; m < 64; m <<= 1) { q0 += __shfl_xor(q0,m,64); q1 += __shfl_xor(q1,m,64); q2 += __shfl_xor(q2,m,64); }
    if (ch == 0) {
        float oaq0 = (float)(q0 + (double)boa2[0]);
        float oaq1 = (float)(q1 + (double)boa2[1]);
        float mmq  = (float)(q2 + (double)boa2[2]);
        float mv0 = (float)pv0, mv1 = (float)pv1;
        float* o = out + (size_t)agent*16;
        o[0] = oaq0; o[1] = oaq1;
        o[2] = mmq + mv1; o[3] = mmq - mv1;
        o[4] = mmq + mv0; o[5] = mmq - mv0;
    }
}

// ---- Attention MLP tail (R5 form, reverted): layer1 bottom half (K=64 over
//      ESC) seeded from per-agent ATtop, then 128->64->1.  fmaf chain =
//      original k=64..127 continuation -> output bitwise identical. ----
__global__ __launch_bounds__(256) void k_attn(
    const float* __restrict__ ATtop, const float* __restrict__ ESC,
    const float* __restrict__ W1,
    const float* __restrict__ W2, const float* __restrict__ b2,
    const float* __restrict__ W3, const float* __restrict__ b3,
    float* __restrict__ out)
{
    __shared__ float escT[64][20];
    __shared__ float h1T[128][20];
    __shared__ float h2[16][68];
    int tid = threadIdx.x;
    int row0 = blockIdx.x*16;
#pragma unroll
    for (int i = 0; i < 4; ++i) {
        int idx = tid + i*256; int r = idx>>6; int j = idx&63;
        escT[j][r] = ESC[(size_t)(row0 + r)*64 + j];
    }
    __syncthreads();
    {   // layer1 bottom: j = tid&127 (coalesced W1), rr = tid>>7 -> rows rr*8..+7
        int j = tid & 127, rr = tid >> 7;
        float acc[8];
#pragma unroll
        for (int r = 0; r < 8; ++r) {
            int ent = row0 + rr*8 + r; int agent = ent/NEN;
            acc[r] = ATtop[(size_t)agent*128 + j];
        }
#pragma unroll 8
        for (int k = 0; k < 64; ++k) {
            float w = W1[(64 + k)*128 + j];
            float4 a0 = *(const float4*)&escT[k][rr*8];
            float4 a1 = *(const float4*)&escT[k][rr*8 + 4];
            acc[0] = fmaf(a0.x, w, acc[0]);
            acc[1] = fmaf(a0.y, w, acc[1]);
            acc[2] = fmaf(a0.z, w, acc[2]);
            acc[3] = fmaf(a0.w, w, acc[3]);
            acc[4] = fmaf(a1.x, w, acc[4]);
            acc[5] = fmaf(a1.y, w, acc[5]);
            acc[6] = fmaf(a1.z, w, acc[6]);
            acc[7] = fmaf(a1.w, w, acc[7]);
        }
        float4 o0 = make_float4(fmaxf(acc[0],0.f), fmaxf(acc[1],0.f),
                                fmaxf(acc[2],0.f), fmaxf(acc[3],0.f));
        float4 o1 = make_float4(fmaxf(acc[4],0.f), fmaxf(acc[5],0.f),
                                fmaxf(acc[6],0.f), fmaxf(acc[7],0.f));
        *(float4*)&h1T[j][rr*8]     = o0;
        *(float4*)&h1T[j][rr*8 + 4] = o1;
    }
    __syncthreads();
    {   // layer2: j2 = tid&63 (coalesced W2), rr2 = tid>>6 -> rows rr2*4..+3
        int j2 = tid & 63, rr2 = tid >> 6;
        float bb = b2[j2];
        float acc[4] = {bb, bb, bb, bb};
#pragma unroll 8
        for (int k = 0; k < 128; ++k) {
            float w = W2[k*64 + j2];
            float4 p = *(const float4*)&h1T[k][rr2*4];
            acc[0] = fmaf(p.x, w, acc[0]);
            acc[1] = fmaf(p.y, w, acc[1]);
            acc[2] = fmaf(p.z, w, acc[2]);
            acc[3] = fmaf(p.w, w, acc[3]);
        }
#pragma unroll
        for (int r = 0; r < 4; ++r) h2[rr2*4+r][j2] = fmaxf(acc[r], 0.f);
    }
    __syncthreads();
    {   // layer3: 16 rows, 16 lanes/row
        int r3 = tid >> 4, l3 = tid & 15;
        float s = 0.f;
#pragma unroll
        for (int q = 0; q < 4; ++q) s = fmaf(h2[r3][l3 + 16*q], W3[l3 + 16*q], s);
#pragma unroll
        for (int m = 1; m < 16; m <<= 1) s += __shfl_xor(s, m, 64);
        if (l3 == 0) {
            int ent = row0 + r3; int agent = ent/NEN; int e = ent%NEN;
            out[(size_t)agent*16 + 6 + e] = s + b3[0];
        }
    }
}

extern "C" void kernel_launch(void* const* d_in, const int* in_sizes, int n_in,
                              void* d_out, int out_size, void* d_ws, size_t ws_size,
                              hipStream_t stream) {
    const float* own  = (const float*)d_in[0];
    const float* ef   = (const float*)d_in[1];
    const float* af   = (const float*)d_in[2];
    const float* W_e1 = (const float*)d_in[3];
    const float* W_e2 = (const float*)d_in[4];
    const float* W_a1 = (const float*)d_in[5];
    const float* W_a2 = (const float*)d_in[6];
    const float* W_f1 = (const float*)d_in[7];
    const float* W_f2 = (const float*)d_in[8];
    const float* W_ie1= (const float*)d_in[9];
    const float* W_ie2= (const float*)d_in[10];
    const float* W_ie3= (const float*)d_in[11];
    const float* W_ia1= (const float*)d_in[12];
    const float* W_ia2= (const float*)d_in[13];
    const float* W_ia3= (const float*)d_in[14];
    const float* W_oa1= (const float*)d_in[15];
    const float* b_oa1= (const float*)d_in[16];
    const float* W_oa2= (const float*)d_in[17];
    const float* b_oa2= (const float*)d_in[18];
    const float* W_at1= (const float*)d_in[19];
    const float* b_at1= (const float*)d_in[20];
    const float* W_at2= (const float*)d_in[21];
    const float* b_at2= (const float*)d_in[22];
    const float* W_at3= (const float*)d_in[23];
    const float* b_at3= (const float*)d_in[24];
    float* out = (float*)d_out;
    float* wsf = (float*)d_ws;
    double* Sd = (double*)d_ws;

    size_t o = (size_t)NDOUBLES*2;
    float*  X_E  = wsf + o; o += (size_t)NEE*128;  // becomes XI_A after k_imp1_both
    float*  X_A  = wsf + o; o += (size_t)NAE*128;
    float*  F1   = wsf + o; o += (size_t)NAG*128;  // becomes ATtop after k_vf_vtop
    float*  SFb  = wsf + o; o += (size_t)NAG*64;
    float*  VT_IE = wsf + o; o += (size_t)NAG*128;
    float*  VT_IA = wsf + o; o += (size_t)NAG*128;
    float*  XI   = wsf + o; o += (size_t)NEE*128;  // XI_E
    float*  Z_IE = wsf + o; o += (size_t)NEE*2;
    float*  Z_IA = wsf + o; o += (size_t)NEE*2;
    float*  ESC  = wsf + o; o += (size_t)NEE*64;   // e_scalar (pair_m2 of X_E)

    double* S_E1 = Sd + DOFF_SE1;  double* S_E2 = Sd + DOFF_SE2;
    double* S_A1 = Sd + DOFF_SA1;  double* S_A2 = Sd + DOFF_SA2;
    double* S_F1 = Sd + DOFF_SF1;  double* S_F2 = Sd + DOFF_SF2;
    double* S_IE1= Sd + DOFF_SIE1; double* S_IE2= Sd + DOFF_SIE2;
    double* S_IA1= Sd + DOFF_SIA1; double* S_IA2= Sd + DOFF_SIA2;
    double* S_IE3= Sd + DOFF_SIE3; double* S_IA3= Sd + DOFF_SIA3;

    const double invRe = 1.0/(double)(NEE*2);
    const double invRa = 1.0/(double)(NAE*2);
    const double invRf = 1.0/(double)(NAG*2);

    hipMemsetAsync(Sd, 0, (size_t)NDOUBLES*sizeof(double), stream);

    k_build_both<<<NBLK_BE + NBLK_BA, 256, 0, stream>>>(
        ef, af, own, W_e1, W_a1, X_E, X_A, S_E1, S_A1);
    k_pair_both<<<NBLK_PE64 + NBLK_PA64, 512, 0, stream>>>(
        X_E, S_E1, S_E2, W_e2, invRe, X_A, S_A1, S_A2, W_a2, invRa);
    k_finalize_pair<<<NEE*32/256, 256, 0, stream>>>(X_E, S_E2, invRe, ESC);
    k_pool_f1<<<NAG/4, 256, 0, stream>>>(X_E, X_A, S_A2, invRa, W_f1, F1, S_F1);
    k_pair_layer<<<NAG/64, 512, 0, stream>>>(F1, S_F1, S_F2, W_f2, invRf);
    k_vf_vtop<<<NAG/4, 256, 0, stream>>>(F1, S_F2, SFb, W_ie1, W_ia1,
                                         W_at1, b_at1, VT_IE, VT_IA, invRf);
    // both importance chains fused: XI_E -> XI, XI_A -> X_E (in place)
    k_imp1_both<<<NEE/32, 512, 0, stream>>>(X_E, VT_IE, VT_IA, W_ie1, W_ia1,
                                            XI, S_IE1, S_IA1);
    k_pair_both<<<NBLK_PE64 + NBLK_PE64, 512, 0, stream>>>(
        XI, S_IE1, S_IE2, W_ie2, invRe, X_E, S_IA1, S_IA2, W_ia2, invRe);
    k_imp3_both<<<2*(NEE/16), 256, 0, stream>>>(XI, X_E, S_IE2, S_IA2,
                                                W_ie3, W_ia3, Z_IE, Z_IA,
                                                S_IE3, S_IA3, invRe);

    k_final_small<<<NAG/4, 256, 0, stream>>>(Z_IE, Z_IA, S_IE3, S_IA3, SFb,
                                             W_oa1, b_oa1, W_oa2, b_oa2, out, invRe);
    k_attn<<<NEE/16, 256, 0, stream>>>(F1, ESC, W_at1, W_at2, b_at2,
                                       W_at3, b_at3, out);
}

// Round 9
// 534.845 us; speedup vs baseline: 1.1062x; 1.0426x over previous
//
#include <hip/hip_runtime.h>
#include <math.h>

// Problem constants
#define BATCH 1024
#define NA 10
#define NEN 10
#define NALY 9
#define NAG (BATCH*NA)          // 10240
#define NEE (NAG*NEN)           // 102400
#define NAE (NAG*NALY)          // 92160
#define EPSF 1e-5f

// f64 replicated qbn-sum buffers (16 replicas), at start of ws (double units)
#define DOFF_SE1 0
#define DOFF_SE2 1024
#define DOFF_SA1 2048
#define DOFF_SA2 3072
#define DOFF_SF1 4096
#define DOFF_SF2 5120
#define DOFF_SIE1 6144
#define DOFF_SIE2 7168
#define DOFF_SIA1 8192
#define DOFF_SIA2 9216
#define DOFF_SIE3 10240   // 16 replicas x stride 8
#define DOFF_SIA3 10368
#define NDOUBLES 16384

#define NBLK_BE (NEE/8)    // 12800
#define NBLK_BA (NAE/8)    // 11520
#define NBLK_PE64 (NEE/64) // 1600
#define NBLK_PA64 (NAE/64) // 1440

__device__ __forceinline__ double sum16vd(const double* __restrict__ S, int ch) {
    double s = 0.0;
#pragma unroll
    for (int r = 0; r < 16; ++r) s += S[r*64 + ch];
    return s;
}
__device__ __forceinline__ double sum16sd8(const double* __restrict__ S) {
    double s = 0.0;
#pragma unroll
    for (int r = 0; r < 16; ++r) s += S[r*8];
    return s;
}
__device__ __forceinline__ float qbn_s(const double* __restrict__ S, int ch, double invRows) {
    float m = (float)(sum16vd(S, ch)*invRows);
    return sqrtf(m + EPSF);
}
__device__ __forceinline__ void red_to_S(const double* red, double* S, int bid, int tid) {
    if (tid < 64) {
        double v = red[tid] + red[tid+64] + red[tid+128] + red[tid+192];
        atomicAdd(&S[(bid & 15)*64 + tid], v);
    }
}
// np-lattice pair mod^2: fl(fl(x0^2)+fl(x1^2)) (no FMA contraction)
__device__ __forceinline__ float pair_m2(float x0, float x1) {
    return __fadd_rn(__fmul_rn(x0,x0), __fmul_rn(x1,x1));
}
// qrelu coeff: bit-identical to mod/fmaxf(1,mod) for finite mod:
//   mod<=1 -> mod/1 == mod exactly; mod>1 -> mod/mod == 1.0f exactly.
__device__ __forceinline__ float qcoef(float mod) {
    return fminf(mod, 1.0f);
}

// ---- build_vec + layer1 GEMM, E and A fused in one launch.
//      Per-output FP sequence identical (REVERSED k, FROZEN). ----
__global__ __launch_bounds__(256) void k_build_both(
    const float* __restrict__ ef, const float* __restrict__ af,
    const float* __restrict__ own,
    const float* __restrict__ We1, const float* __restrict__ Wa1,
    float* __restrict__ XE, float* __restrict__ XA,
    double* __restrict__ SE1, double* __restrict__ SA1)
{
    bool isA = (blockIdx.x >= NBLK_BE);
    int blk = isA ? (blockIdx.x - NBLK_BE) : blockIdx.x;
    const float* feats = isA ? af : ef;
    const float* W1    = isA ? Wa1 : We1;
    float* X           = isA ? XA : XE;
    double* S1         = isA ? SA1 : SE1;
    int nEntPerAgent   = isA ? NALY : NEN;

    __shared__ float wlds[19*64];
    __shared__ float gpc[16][19];     // (el*2+c, k): pc * g  precomputed
    __shared__ double red[256];
    int tid = threadIdx.x;
    for (int i = tid; i < 19*64; i += 256) wlds[i] = W1[i];
    if (tid < 152) {
        int el = tid / 19, chg = tid % 19;
        int ent = blk*8 + el;
        const float* f = feats + (size_t)ent*9;
        int agent = ent / nEntPerAgent;
        float px = f[2], py = f[3];
        float pm = sqrtf(__fadd_rn(__fmul_rn(px,px), __fmul_rn(py,py)));
        float val;
        if (chg == 0) val = 1.f;
        else if (chg < 8) {
            int j = chg - 1;
            int fi = (j < 2) ? j : (j + 2);
            float o = f[fi];
            float om = sqrtf(__fmul_rn(__fmul_rn(2.0f,o),o));
            val = (pm == 0.f) ? 0.f : __fdiv_rn(om, pm);
        } else {
            float o = own[(size_t)agent*11 + (chg-8)];
            float t = __fmul_rn(o,o);
            float om = sqrtf(__fadd_rn(t,t));
            val = (pm == 0.f) ? 0.f : __fdiv_rn(om, pm);
        }
        // same bits as the old per-lane __fmul_rn(pc, g[el][k])
        gpc[el*2 + 0][chg] = __fmul_rn(px, val);
        gpc[el*2 + 1][chg] = __fmul_rn(py, val);
    }
    __syncthreads();
    int l = tid >> 7, c = (tid >> 6) & 1, ch = tid & 63;
    float wreg[19];
#pragma unroll
    for (int k = 0; k < 19; ++k) wreg[k] = wlds[k*64+ch];
    double lr = 0.0;
#pragma unroll
    for (int i = 0; i < 4; ++i) {
        int el = l + 2*i;
        int ent = blk*8 + el;
        int row = el*2 + c;
        float acc = 0.f;
#pragma unroll
        for (int k = 18; k >= 0; --k) {            // REVERSED k (frozen)
            acc = fmaf(gpc[row][k], wreg[k], acc);
        }
        X[(size_t)ent*128 + c*64 + ch] = acc;
        lr += (double)acc * (double)acc;
    }
    red[tid] = lr;
    __syncthreads();
    red_to_S(red, S1, blk, tid);
}

// ---- pair-layer core: 512 threads, 64 rows/block, 2 rows/thread.
//      dredw aliased into ybuf (barrier after GEMM makes it race-free).
//      Each output's fmaf chain (REVERSED k) is unchanged bit-for-bit. ----
__device__ __forceinline__ void pair_layer_body(
    float* __restrict__ X, const double* __restrict__ Sin, double* __restrict__ Sout,
    const float* __restrict__ W, double invRows, int blk)
{
    __shared__ float wlds[4096];
    __shared__ __align__(16) float ybuf[64][132];
    __shared__ float ss[64];
    double* dredw = (double*)&ybuf[0][0];   // 8 waves x 64 ch = 4 KB, aliased
    int tid = threadIdx.x;
    for (int i = tid; i < 4096; i += 512) wlds[i] = W[i];
    if (tid < 64) ss[tid] = qbn_s(Sin, tid, invRows);
    __syncthreads();
    int rl = tid >> 4;                 // 0..31
    int ch0 = (tid & 15) * 4;
#pragma unroll
    for (int h = 0; h < 2; ++h) {
        int r = rl + h*32;
        size_t row = (size_t)blk*64 + r;
        float4 xv0 = *(const float4*)&X[row*128 + ch0];
        float4 xv1 = *(const float4*)&X[row*128 + 64 + ch0];
        float xs0[4] = {xv0.x,xv0.y,xv0.z,xv0.w};
        float xs1[4] = {xv1.x,xv1.y,xv1.z,xv1.w};
        float y0[4], y1[4];
#pragma unroll
        for (int i = 0; i < 4; ++i) {
            float s = ss[ch0+i];
            float u0 = xs0[i]/s, u1 = xs1[i]/s;
            float mod = sqrtf(pair_m2(u0,u1));
            float cf = qcoef(mod);
            y0[i] = __fmul_rn(u0,cf);
            y1[i] = __fmul_rn(u1,cf);
        }
        *(float4*)&ybuf[r][2*ch0]     = make_float4(y0[0],y1[0],y0[1],y1[1]);
        *(float4*)&ybuf[r][2*ch0 + 4] = make_float4(y0[2],y1[2],y0[3],y1[3]);
    }
    __syncthreads();
    float a0[4] = {0.f,0.f,0.f,0.f};
    float a1[4] = {0.f,0.f,0.f,0.f};
    float c0[4] = {0.f,0.f,0.f,0.f};
    float c1[4] = {0.f,0.f,0.f,0.f};
#pragma unroll
    for (int k = 63; k >= 1; k -= 2) {           // REVERSED k (frozen)
        float4 wk  = *(const float4*)&wlds[k*64 + ch0];
        float4 wk1 = *(const float4*)&wlds[(k-1)*64 + ch0];
        float4 ya  = *(const float4*)&ybuf[rl][2*k - 2];
        float4 yb  = *(const float4*)&ybuf[rl+32][2*k - 2];
        float wkv[4]  = {wk.x,wk.y,wk.z,wk.w};
        float wk1v[4] = {wk1.x,wk1.y,wk1.z,wk1.w};
#pragma unroll
        for (int i = 0; i < 4; ++i) {
            a0[i] = fmaf(ya.z, wkv[i], a0[i]);
            a1[i] = fmaf(ya.w, wkv[i], a1[i]);
        }
#pragma unroll
        for (int i = 0; i < 4; ++i) {
            a0[i] = fmaf(ya.x, wk1v[i], a0[i]);
            a1[i] = fmaf(ya.y, wk1v[i], a1[i]);
        }
#pragma unroll
        for (int i = 0; i < 4; ++i) {
            c0[i] = fmaf(yb.z, wkv[i], c0[i]);
            c1[i] = fmaf(yb.w, wkv[i], c1[i]);
        }
#pragma unroll
        for (int i = 0; i < 4; ++i) {
            c0[i] = fmaf(yb.x, wk1v[i], c0[i]);
            c1[i] = fmaf(yb.y, wk1v[i], c1[i]);
        }
    }
    size_t rowA = (size_t)blk*64 + rl;
    size_t rowB = rowA + 32;
    *(float4*)&X[rowA*128 + ch0]      = make_float4(a0[0],a0[1],a0[2],a0[3]);
    *(float4*)&X[rowA*128 + 64 + ch0] = make_float4(a1[0],a1[1],a1[2],a1[3]);
    *(float4*)&X[rowB*128 + ch0]      = make_float4(c0[0],c0[1],c0[2],c0[3]);
    *(float4*)&X[rowB*128 + 64 + ch0] = make_float4(c1[0],c1[1],c1[2],c1[3]);
    __syncthreads();   // ybuf reads done; safe to reuse as dredw
    {
        int wv = tid >> 6;             // 0..7
#pragma unroll
        for (int i = 0; i < 4; ++i) {
            double d = (double)a0[i]*a0[i] + (double)a1[i]*a1[i]
                     + (double)c0[i]*c0[i] + (double)c1[i]*c1[i];
            d += __shfl_xor(d, 16, 64);
            d += __shfl_xor(d, 32, 64);
            if ((tid & 48) == 0) dredw[wv*64 + ch0+i] = d;
        }
    }
    __syncthreads();
    if (tid < 64) {
        double v = 0.0;
#pragma unroll
        for (int w = 0; w < 8; ++w) v += dredw[w*64 + tid];
        atomicAdd(&Sout[(blk & 15)*64 + tid], v);
    }
}

// ---- pair layer for two X-streams in one launch (split at NBLK_PE64). ----
__global__ __launch_bounds__(512) void k_pair_both(
    float* __restrict__ XE, const double* __restrict__ SE1, double* __restrict__ SE2,
    const float* __restrict__ We2, double invRe,
    float* __restrict__ XA, const double* __restrict__ SA1, double* __restrict__ SA2,
    const float* __restrict__ Wa2, double invRa)
{
    if (blockIdx.x < NBLK_PE64)
        pair_layer_body(XE, SE1, SE2, We2, invRe, blockIdx.x);
    else
        pair_layer_body(XA, SA1, SA2, Wa2, invRa, blockIdx.x - NBLK_PE64);
}

// ---- generic pair layer (F1). ----
__global__ __launch_bounds__(512) void k_pair_layer(
    float* __restrict__ X, const double* __restrict__ Sin, double* __restrict__ Sout,
    const float* __restrict__ W, double invRows)
{
    pair_layer_body(X, Sin, Sout, W, invRows, blockIdx.x);
}

// ---- Finalize (E only): y = qrelu(qbn(x)) in place + ESC = pair_m2. ----
__global__ __launch_bounds__(256) void k_finalize_pair(
    float* __restrict__ X, const double* __restrict__ S2, double invRows,
    float* __restrict__ ESC)
{
    __shared__ float ss[64];
    if (threadIdx.x < 64) ss[threadIdx.x] = qbn_s(S2, threadIdx.x, invRows);
    int t = blockIdx.x*256 + threadIdx.x;
    int rl = t >> 4;              // (ent*2 + c) row index
    int ch0 = (t & 15) * 4;
    size_t base    = (size_t)rl*64 + ch0;
    size_t partner = (size_t)(rl ^ 1)*64 + ch0;
    float4 xv  = *(const float4*)&X[base];
    float4 xov = *(const float4*)&X[partner];
    __syncthreads();
    float xs[4]  = {xv.x,xv.y,xv.z,xv.w};
    float xos[4] = {xov.x,xov.y,xov.z,xov.w};
    float r[4], esc[4];
    int c = rl & 1;
#pragma unroll
    for (int i = 0; i < 4; ++i) {
        float s = ss[ch0+i];
        float u  = xs[i]/s;
        float uo = xos[i]/s;
        float u0 = (c==0) ? u : uo, u1 = (c==0) ? uo : u;
        float mod = sqrtf(pair_m2(u0,u1));
        float cf = qcoef(mod);
        r[i] = __fmul_rn(u, cf);
        if (c == 0) {
            float y1v = __fmul_rn(uo, cf);   // identical bits to partner's write
            esc[i] = pair_m2(r[i], y1v);
        }
    }
    *(float4*)&X[base] = make_float4(r[0],r[1],r[2],r[3]);
    if (c == 0) {
        int ent = rl >> 1;
        *(float4*)&ESC[(size_t)ent*64 + ch0] = make_float4(esc[0],esc[1],esc[2],esc[3]);
    }
}

// ---- Pool + f1 GEMM, ally finalize fused (identical op sequence). ----
__global__ __launch_bounds__(256) void k_pool_f1(
    const float* __restrict__ XE, const float* __restrict__ XAraw,
    const double* __restrict__ SA2, double invRa,
    const float* __restrict__ Wf1, float* __restrict__ F1, double* __restrict__ Sf1)
{
    __shared__ float wlds[4096];
    __shared__ float v[4][2][64];
    __shared__ float ssa[64];
    __shared__ double red[256];
    int tid = threadIdx.x;
    for (int i = tid; i < 4096; i += 256) wlds[i] = Wf1[i];
    if (tid < 64) ssa[tid] = qbn_s(SA2, tid, invRa);
    __syncthreads();
    int grp = tid>>6, ch = tid&63;
    int agent = blockIdx.x*4 + grp;
    float best = -1.f, v0 = 0.f, v1 = 0.f;
    for (int e = 0; e < NEN; ++e) {
        size_t b = (size_t)(agent*NEN+e)*128;
        float x0 = XE[b+ch], x1 = XE[b+64+ch];
        float m2 = pair_m2(x0,x1);
        if (m2 > best) { best = m2; v0 = x0; v1 = x1; }
    }
    float sa = ssa[ch];
    for (int l = 0; l < NALY; ++l) {
        size_t b = (size_t)(agent*NALY+l)*128;
        float r0 = XAraw[b+ch], r1 = XAraw[b+64+ch];
        float u0 = r0/sa, u1 = r1/sa;
        float modf = sqrtf(pair_m2(u0,u1));
        float cff = qcoef(modf);
        float x0 = __fmul_rn(u0,cff), x1 = __fmul_rn(u1,cff);
        float m2 = pair_m2(x0,x1);
        if (m2 > best) { best = m2; v0 = x0; v1 = x1; }
    }
    v[grp][0][ch] = v0; v[grp][1][ch] = v1;
    __syncthreads();
    float a0 = 0.f, a1 = 0.f;
#pragma unroll
    for (int k = 0; k < 64; ++k) {
        float w = wlds[k*64+ch];
        a0 = fmaf(v[grp][0][k], w, a0);
        a1 = fmaf(v[grp][1][k], w, a1);
    }
    F1[(size_t)agent*128+ch] = a0; F1[(size_t)agent*128+64+ch] = a1;
    red[tid] = (double)a0*a0 + (double)a1*a1;
    __syncthreads();
    red_to_S(red, Sf1, blockIdx.x, tid);
}

// ---- vf finalize + SFb + VT = vf @ W1top for both imp chains
//      + ATtop = b_at1 + sf @ W_at1[0:64] (hoisted attn layer1 top half).
//      ATtop overwrites F1 in place (dead after; reads precede barrier). ----
__global__ __launch_bounds__(256) void k_vf_vtop(
    float* __restrict__ F1, const double* __restrict__ Sf2,
    float* __restrict__ SFb,
    const float* __restrict__ Wie1, const float* __restrict__ Wia1,
    const float* __restrict__ Wat1, const float* __restrict__ bat1,
    float* __restrict__ VTie, float* __restrict__ VTia, double invRows)
{
    __shared__ float wie[4096];
    __shared__ float wia[4096];
    __shared__ float vf[4][2][64];
    __shared__ float sfv[4][64];
    int tid = threadIdx.x;
    for (int i = tid; i < 4096; i += 256) { wie[i] = Wie1[i]; wia[i] = Wia1[i]; }
    int grp = tid>>6, ch = tid&63;
    int agent = blockIdx.x*4 + grp;
    float x0 = F1[(size_t)agent*128+ch], x1 = F1[(size_t)agent*128+64+ch];
    float s = qbn_s(Sf2, ch, invRows);
    float u0 = x0/s, u1 = x1/s;
    float mod = sqrtf(pair_m2(u0,u1));
    float cf = qcoef(mod);
    float y0 = __fmul_rn(u0,cf), y1 = __fmul_rn(u1,cf);
    vf[grp][0][ch] = y0; vf[grp][1][ch] = y1;
    float sf = pair_m2(y0,y1);
    SFb[(size_t)agent*64+ch] = sf;
    sfv[grp][ch] = sf;
    __syncthreads();
    float a0=0.f,a1=0.f,b0=0.f,b1=0.f;
    float at0 = bat1[ch], at1 = bat1[64+ch];
#pragma unroll
    for (int k = 0; k < 64; ++k) {
        float f0 = vf[grp][0][k], f1 = vf[grp][1][k];
        a0 = fmaf(f0, wie[k*64+ch], a0); a1 = fmaf(f1, wie[k*64+ch], a1);
        b0 = fmaf(f0, wia[k*64+ch], b0); b1 = fmaf(f1, wia[k*64+ch], b1);
        float sv = sfv[grp][k];
        at0 = fmaf(sv, Wat1[k*128 + ch], at0);
        at1 = fmaf(sv, Wat1[k*128 + 64 + ch], at1);
    }
    VTie[(size_t)agent*128+ch] = a0; VTie[(size_t)agent*128+64+ch] = a1;
    VTia[(size_t)agent*128+ch] = b0; VTia[(size_t)agent*128+64+ch] = b1;
    F1[(size_t)agent*128+ch] = at0; F1[(size_t)agent*128+64+ch] = at1;
}

// ---- imp layer1 BOTH chains: 512 threads, 32 ents/block, 2 rows/thread.
//      dredw aliased into xt (barrier after GEMM). Per-output chains frozen. ----
__global__ __launch_bounds__(512) void k_imp1_both(
    float* __restrict__ XE,
    const float* __restrict__ VTe, const float* __restrict__ VTa,
    const float* __restrict__ W1e, const float* __restrict__ W1a,
    float* __restrict__ XIe,
    double* __restrict__ S1e, double* __restrict__ S1a)
{
    __shared__ float wldsE[4096];
    __shared__ float wldsA[4096];
    __shared__ __align__(16) float xt[64][68];
    double* dredwE = (double*)&xt[0][0];        // 8 waves x 64 ch
    double* dredwA = dredwE + 512;              // next 4 KB
    int tid = threadIdx.x;
    for (int i = tid; i < 4096; i += 512) { wldsE[i] = W1e[4096 + i]; wldsA[i] = W1a[4096 + i]; }
#pragma unroll
    for (int i = 0; i < 2; ++i) {
        int fidx = tid + i*512;               // float4 index 0..1023
        int r = fidx >> 4;                    // row 0..63 (= ent_local*2 + c)
        int kq = (fidx & 15) * 4;
        float4 t4 = *(const float4*)&XE[(size_t)blockIdx.x*4096 + (size_t)fidx*4];
        *(float4*)&xt[r][kq] = t4;
    }
    __syncthreads();
    int rl = tid >> 4;                        // 0..31
    int ch0 = (tid & 15) * 4;
    int entA = blockIdx.x*32 + (rl >> 1);     // rows rl      -> ents 0..15
    int entB = entA + 16;                     // rows rl+32   -> ents 16..31
    int c = rl & 1;
    int agentA = entA / NEN, agentB = entB / NEN;
    float4 vteA = *(const float4*)&VTe[(size_t)agentA*128 + c*64 + ch0];
    float4 vtaA = *(const float4*)&VTa[(size_t)agentA*128 + c*64 + ch0];
    float4 vteB = *(const float4*)&VTe[(size_t)agentB*128 + c*64 + ch0];
    float4 vtaB = *(const float4*)&VTa[(size_t)agentB*128 + c*64 + ch0];
    float accEA[4] = {vteA.x, vteA.y, vteA.z, vteA.w};
    float accAA[4] = {vtaA.x, vtaA.y, vtaA.z, vtaA.w};
    float accEB[4] = {vteB.x, vteB.y, vteB.z, vteB.w};
    float accAB[4] = {vtaB.x, vtaB.y, vtaB.z, vtaB.w};
#pragma unroll
    for (int k = 0; k < 64; k += 4) {
        float4 xa4 = *(const float4*)&xt[rl][k];
        float4 xb4 = *(const float4*)&xt[rl+32][k];
        float xa[4] = {xa4.x, xa4.y, xa4.z, xa4.w};
        float xb[4] = {xb4.x, xb4.y, xb4.z, xb4.w};
#pragma unroll
        for (int kk = 0; kk < 4; ++kk) {
            float4 we = *(const float4*)&wldsE[(k+kk)*64 + ch0];
            accEA[0] = fmaf(xa[kk], we.x, accEA[0]);
            accEA[1] = fmaf(xa[kk], we.y, accEA[1]);
            accEA[2] = fmaf(xa[kk], we.z, accEA[2]);
            accEA[3] = fmaf(xa[kk], we.w, accEA[3]);
            accEB[0] = fmaf(xb[kk], we.x, accEB[0]);
            accEB[1] = fmaf(xb[kk], we.y, accEB[1]);
            accEB[2] = fmaf(xb[kk], we.z, accEB[2]);
            accEB[3] = fmaf(xb[kk], we.w, accEB[3]);
            float4 wa = *(const float4*)&wldsA[(k+kk)*64 + ch0];
            accAA[0] = fmaf(xa[kk], wa.x, accAA[0]);
            accAA[1] = fmaf(xa[kk], wa.y, accAA[1]);
            accAA[2] = fmaf(xa[kk], wa.z, accAA[2]);
            accAA[3] = fmaf(xa[kk], wa.w, accAA[3]);
            accAB[0] = fmaf(xb[kk], wa.x, accAB[0]);
            accAB[1] = fmaf(xb[kk], wa.y, accAB[1]);
            accAB[2] = fmaf(xb[kk], wa.z, accAB[2]);
            accAB[3] = fmaf(xb[kk], wa.w, accAB[3]);
        }
    }
    *(float4*)&XIe[(size_t)entA*128 + c*64 + ch0] = make_float4(accEA[0],accEA[1],accEA[2],accEA[3]);
    *(float4*)&XIe[(size_t)entB*128 + c*64 + ch0] = make_float4(accEB[0],accEB[1],accEB[2],accEB[3]);
    *(float4*)&XE [(size_t)entA*128 + c*64 + ch0] = make_float4(accAA[0],accAA[1],accAA[2],accAA[3]);
    *(float4*)&XE [(size_t)entB*128 + c*64 + ch0] = make_float4(accAB[0],accAB[1],accAB[2],accAB[3]);
    __syncthreads();   // xt reads done; safe to reuse as dredw
    int wv = tid >> 6;
#pragma unroll
    for (int i = 0; i < 4; ++i) {
        double dE = (double)accEA[i]*accEA[i] + (double)accEB[i]*accEB[i];
        dE += __shfl_xor(dE, 16, 64);
        dE += __shfl_xor(dE, 32, 64);
        double dA = (double)accAA[i]*accAA[i] + (double)accAB[i]*accAB[i];
        dA += __shfl_xor(dA, 16, 64);
        dA += __shfl_xor(dA, 32, 64);
        if ((tid & 48) == 0) {
            dredwE[wv*64 + ch0+i] = dE;
            dredwA[wv*64 + ch0+i] = dA;
        }
    }
    __syncthreads();
    if (tid < 64) {
        double vE = 0.0, vA = 0.0;
#pragma unroll
        for (int w = 0; w < 8; ++w) { vE += dredwE[w*64 + tid]; vA += dredwA[w*64 + tid]; }
        atomicAdd(&S1e[(blockIdx.x & 15)*64 + tid], vE);
        atomicAdd(&S1a[(blockIdx.x & 15)*64 + tid], vA);
    }
}

// ---- imp layer3 BOTH chains in one launch (block-range split). ----
__global__ __launch_bounds__(256) void k_imp3_both(
    const float* __restrict__ XIe, const float* __restrict__ XIa,
    const double* __restrict__ S2e, const double* __restrict__ S2a,
    const float* __restrict__ W3e, const float* __restrict__ W3a,
    float* __restrict__ Ze, float* __restrict__ Za,
    double* __restrict__ S3e, double* __restrict__ S3a, double invRows)
{
    bool isA = (blockIdx.x >= (NEE/16));
    int blk = isA ? (blockIdx.x - NEE/16) : blockIdx.x;
    const float* XI = isA ? XIa : XIe;
    const double* S2 = isA ? S2a : S2e;
    const float* W3 = isA ? W3a : W3e;
    float* Z = isA ? Za : Ze;
    double* S3 = isA ? S3a : S3e;

    __shared__ float ss[64];
    __shared__ double red4[4];
    int tid = threadIdx.x; int grp = tid>>6, ch = tid&63;
    if (tid < 64) ss[tid] = qbn_s(S2, tid, invRows);
    __syncthreads();
    float s = ss[ch];
    double w3 = (double)W3[ch];
    double lr3 = 0.0;
#pragma unroll
    for (int i = 0; i < 4; ++i) {
        int ent = blk*16 + grp + 4*i;
        float x0 = XI[(size_t)ent*128+ch], x1 = XI[(size_t)ent*128+64+ch];
        float u0 = x0/s, u1 = x1/s;
        float mod = sqrtf(pair_m2(u0,u1));
        float cf = qcoef(mod);
        double v0 = (double)__fmul_rn(u0,cf) * w3;
        double v1 = (double)__fmul_rn(u1,cf) * w3;
#pragma unroll
        for (int m = 1; m < 64; m <<= 1) { v0 += __shfl_xor(v0,m,64); v1 += __shfl_xor(v1,m,64); }
        if (ch == 0) {
            float z0 = (float)v0, z1 = (float)v1;
            Z[(size_t)ent*2] = z0; Z[(size_t)ent*2+1] = z1;
            lr3 += (double)z0*z0 + (double)z1*z1;
        }
    }
    if (ch == 0) red4[grp] = lr3;
    __syncthreads();
    if (tid == 0) atomicAdd(&S3[(blk & 15)*8], red4[0]+red4[1]+red4[2]+red4[3]);
}

// ---- move_vec + oaq head + output cols 0..5. ----
__global__ __launch_bounds__(256) void k_final_small(
    const float* __restrict__ Zie, const float* __restrict__ Zia,
    const double* __restrict__ Sie3, const double* __restrict__ Sia3,
    const float* __restrict__ SFb,
    const float* __restrict__ Woa1, const float* __restrict__ boa1,
    const float* __restrict__ Woa2, const float* __restrict__ boa2,
    float* __restrict__ out, double invRows)
{
    __shared__ float sflds[4][64];
    int tid = threadIdx.x; int grp = tid>>6, ch = tid&63;
    int agent = blockIdx.x*4 + grp;
    float sie = sqrtf((float)(sum16sd8(Sie3)*invRows) + EPSF);
    float sia = sqrtf((float)(sum16sd8(Sia3)*invRows) + EPSF);
    double pv0 = 0.0, pv1 = 0.0;
    if (ch < NEN) {
        int ent = agent*NEN + ch;
        float z0 = Zie[(size_t)ent*2]/sie, z1 = Zie[(size_t)ent*2+1]/sie;
        float mod = sqrtf(pair_m2(z0,z1)); float cf = qcoef(mod);
        pv0 = (double)__fmul_rn(z0,cf); pv1 = (double)__fmul_rn(z1,cf);
        z0 = Zia[(size_t)ent*2]/sia; z1 = Zia[(size_t)ent*2+1]/sia;
        mod = sqrtf(pair_m2(z0,z1)); cf = qcoef(mod);
        pv0 += (double)__fmul_rn(z0,cf); pv1 += (double)__fmul_rn(z1,cf);
    }
#pragma unroll
    for (int m = 1; m < 64; m <<= 1) { pv0 += __shfl_xor(pv0,m,64); pv1 += __shfl_xor(pv1,m,64); }
    sflds[grp][ch] = SFb[(size_t)agent*64+ch];
    __syncthreads();
    double hd = (double)boa1[ch];
#pragma unroll
    for (int k = 0; k < 64; ++k) hd += (double)sflds[grp][k]*(double)Woa1[k*64+ch];
    float h = fmaxf((float)hd, 0.f);
    double q0 = (double)h*(double)Woa2[ch*3+0];
    double q1 = (double)h*(double)Woa2[ch*3+1];
    double q2 = (double)h*(double)Woa2[ch*3+2];
#pragma unroll
    for (int m = 1; m < 64; m <<= 1) { q0 += __shfl_xor(q0,m,64); q1 += __shfl_xor(q1,m,64); q2 += __shfl_xor(q2,m,64); }
    if (ch == 0) {
        float oaq0 = (float)(q0 + (double)boa2[0]);
        float oaq1 = (float)(q1 + (double)boa2[1]);
        float mmq  = (float)(q2 + (double)boa2[2]);
        float mv0 = (float)pv0, mv1 = (float)pv1;
        float* o = out + (size_t)agent*16;
        o[0] = oaq0; o[1] = oaq1;
        o[2] = mmq + mv1; o[3] = mmq - mv1;
        o[4] = mmq + mv0; o[5] = mmq - mv0;
    }
}

// ---- Attention MLP tail, R8: 32 rows/block, SAME lane mappings as R5
//      (j-stride-1 in all LDS leading indices -> no new bank conflicts),
//      each thread owning 2x the rows so W-load instrs per output halve.
//      Layer1: j=tid&127 x 16 rows (acc[16]); layer2: j2=tid&63 x 8 rows;
//      layer3: exact 16-lane form run twice.  h2 aliased into escT.
//      Per-output fmaf chains (init, then k ascending) bit-identical. ----
__global__ __launch_bounds__(256) void k_attn(
    const float* __restrict__ ATtop, const float* __restrict__ ESC,
    const float* __restrict__ W1,
    const float* __restrict__ W2, const float* __restrict__ b2,
    const float* __restrict__ W3, const float* __restrict__ b3,
    float* __restrict__ out)
{
    __shared__ __align__(16) float escT[64][36];   // [j][r], r=0..31
    __shared__ __align__(16) float h1T[128][36];   // [j][r]
    float (*h2)[68] = (float(*)[68])&escT[0][0];   // 32x68=2176 <= 64x36=2304
    int tid = threadIdx.x;
    int row0 = blockIdx.x*32;
#pragma unroll
    for (int i = 0; i < 8; ++i) {
        int idx = tid + i*256; int r = idx>>6; int j = idx&63;
        escT[j][r] = ESC[(size_t)(row0 + r)*64 + j];
    }
    __syncthreads();
    {   // layer1 bottom: j = tid&127 (stride-1 lanes), rr = tid>>7 -> rows rr*16..+15
        int j = tid & 127, rr = tid >> 7;
        float acc[16];
#pragma unroll
        for (int r = 0; r < 16; ++r) {
            int ent = row0 + rr*16 + r; int agent = ent/NEN;
            acc[r] = ATtop[(size_t)agent*128 + j];
        }
#pragma unroll 4
        for (int k = 0; k < 64; ++k) {
            float w = W1[(size_t)(64 + k)*128 + j];
            float4 a0 = *(const float4*)&escT[k][rr*16];
            float4 a1 = *(const float4*)&escT[k][rr*16 + 4];
            float4 a2 = *(const float4*)&escT[k][rr*16 + 8];
            float4 a3 = *(const float4*)&escT[k][rr*16 + 12];
            acc[0]  = fmaf(a0.x, w, acc[0]);
            acc[1]  = fmaf(a0.y, w, acc[1]);
            acc[2]  = fmaf(a0.z, w, acc[2]);
            acc[3]  = fmaf(a0.w, w, acc[3]);
            acc[4]  = fmaf(a1.x, w, acc[4]);
            acc[5]  = fmaf(a1.y, w, acc[5]);
            acc[6]  = fmaf(a1.z, w, acc[6]);
            acc[7]  = fmaf(a1.w, w, acc[7]);
            acc[8]  = fmaf(a2.x, w, acc[8]);
            acc[9]  = fmaf(a2.y, w, acc[9]);
            acc[10] = fmaf(a2.z, w, acc[10]);
            acc[11] = fmaf(a2.w, w, acc[11]);
            acc[12] = fmaf(a3.x, w, acc[12]);
            acc[13] = fmaf(a3.y, w, acc[13]);
            acc[14] = fmaf(a3.z, w, acc[14]);
            acc[15] = fmaf(a3.w, w, acc[15]);
        }
#pragma unroll
        for (int q = 0; q < 4; ++q) {
            float4 o = make_float4(fmaxf(acc[q*4+0],0.f), fmaxf(acc[q*4+1],0.f),
                                   fmaxf(acc[q*4+2],0.f), fmaxf(acc[q*4+3],0.f));
            *(float4*)&h1T[j][rr*16 + q*4] = o;
        }
    }
    __syncthreads();
    {   // layer2: j2 = tid&63 (stride-1 lanes), rr2 = tid>>6 -> rows rr2*8..+7
        int j2 = tid & 63, rr2 = tid >> 6;
        float bb = b2[j2];
        float acc[8];
#pragma unroll
        for (int r = 0; r < 8; ++r) acc[r] = bb;
#pragma unroll 8
        for (int k = 0; k < 128; ++k) {
            float w = W2[(size_t)k*64 + j2];
            float4 p0 = *(const float4*)&h1T[k][rr2*8];
            float4 p1 = *(const float4*)&h1T[k][rr2*8 + 4];
            acc[0] = fmaf(p0.x, w, acc[0]);
            acc[1] = fmaf(p0.y, w, acc[1]);
            acc[2] = fmaf(p0.z, w, acc[2]);
            acc[3] = fmaf(p0.w, w, acc[3]);
            acc[4] = fmaf(p1.x, w, acc[4]);
            acc[5] = fmaf(p1.y, w, acc[5]);
            acc[6] = fmaf(p1.z, w, acc[6]);
            acc[7] = fmaf(p1.w, w, acc[7]);
        }
#pragma unroll
        for (int r = 0; r < 8; ++r) h2[rr2*8+r][j2] = fmaxf(acc[r], 0.f);
    }
    __syncthreads();
    {   // layer3: two halves of 16 rows; exact 16-lane structure preserved
#pragma unroll
        for (int half = 0; half < 2; ++half) {
            int r3 = (tid >> 4) + half*16, l3 = tid & 15;
            float s = 0.f;
#pragma unroll
            for (int q = 0; q < 4; ++q) s = fmaf(h2[r3][l3 + 16*q], W3[l3 + 16*q], s);
#pragma unroll
            for (int m = 1; m < 16; m <<= 1) s += __shfl_xor(s, m, 64);
            if (l3 == 0) {
                int ent = row0 + r3; int agent = ent/NEN; int e = ent%NEN;
                out[(size_t)agent*16 + 6 + e] = s + b3[0];
            }
        }
    }
}

extern "C" void kernel_launch(void* const* d_in, const int* in_sizes, int n_in,
                              void* d_out, int out_size, void* d_ws, size_t ws_size,
                              hipStream_t stream) {
    const float* own  = (const float*)d_in[0];
    const float* ef   = (const float*)d_in[1];
    const float* af   = (const float*)d_in[2];
    const float* W_e1 = (const float*)d_in[3];
    const float* W_e2 = (const float*)d_in[4];
    const float* W_a1 = (const float*)d_in[5];
    const float* W_a2 = (const float*)d_in[6];
    const float* W_f1 = (const float*)d_in[7];
    const float* W_f2 = (const float*)d_in[8];
    const float* W_ie1= (const float*)d_in[9];
    const float* W_ie2= (const float*)d_in[10];
    const float* W_ie3= (const float*)d_in[11];
    const float* W_ia1= (const float*)d_in[12];
    const float* W_ia2= (const float*)d_in[13];
    const float* W_ia3= (const float*)d_in[14];
    const float* W_oa1= (const float*)d_in[15];
    const float* b_oa1= (const float*)d_in[16];
    const float* W_oa2= (const float*)d_in[17];
    const float* b_oa2= (const float*)d_in[18];
    const float* W_at1= (const float*)d_in[19];
    const float* b_at1= (const float*)d_in[20];
    const float* W_at2= (const float*)d_in[21];
    const float* b_at2= (const float*)d_in[22];
    const float* W_at3= (const float*)d_in[23];
    const float* b_at3= (const float*)d_in[24];
    float* out = (float*)d_out;
    float* wsf = (float*)d_ws;
    double* Sd = (double*)d_ws;

    size_t o = (size_t)NDOUBLES*2;
    float*  X_E  = wsf + o; o += (size_t)NEE*128;  // becomes XI_A after k_imp1_both
    float*  X_A  = wsf + o; o += (size_t)NAE*128;
    float*  F1   = wsf + o; o += (size_t)NAG*128;  // becomes ATtop after k_vf_vtop
    float*  SFb  = wsf + o; o += (size_t)NAG*64;
    float*  VT_IE = wsf + o; o += (size_t)NAG*128;
    float*  VT_IA = wsf + o; o += (size_t)NAG*128;
    float*  XI   = wsf + o; o += (size_t)NEE*128;  // XI_E
    float*  Z_IE = wsf + o; o += (size_t)NEE*2;
    float*  Z_IA = wsf + o; o += (size_t)NEE*2;
    float*  ESC  = wsf + o; o += (size_t)NEE*64;   // e_scalar (pair_m2 of X_E)

    double* S_E1 = Sd + DOFF_SE1;  double* S_E2 = Sd + DOFF_SE2;
    double* S_A1 = Sd + DOFF_SA1;  double* S_A2 = Sd + DOFF_SA2;
    double* S_F1 = Sd + DOFF_SF1;  double* S_F2 = Sd + DOFF_SF2;
    double* S_IE1= Sd + DOFF_SIE1; double* S_IE2= Sd + DOFF_SIE2;
    double* S_IA1= Sd + DOFF_SIA1; double* S_IA2= Sd + DOFF_SIA2;
    double* S_IE3= Sd + DOFF_SIE3; double* S_IA3= Sd + DOFF_SIA3;

    const double invRe = 1.0/(double)(NEE*2);
    const double invRa = 1.0/(double)(NAE*2);
    const double invRf = 1.0/(double)(NAG*2);

    hipMemsetAsync(Sd, 0, (size_t)NDOUBLES*sizeof(double), stream);

    k_build_both<<<NBLK_BE + NBLK_BA, 256, 0, stream>>>(
        ef, af, own, W_e1, W_a1, X_E, X_A, S_E1, S_A1);
    k_pair_both<<<NBLK_PE64 + NBLK_PA64, 512, 0, stream>>>(
        X_E, S_E1, S_E2, W_e2, invRe, X_A, S_A1, S_A2, W_a2, invRa);
    k_finalize_pair<<<NEE*32/256, 256, 0, stream>>>(X_E, S_E2, invRe, ESC);
    k_pool_f1<<<NAG/4, 256, 0, stream>>>(X_E, X_A, S_A2, invRa, W_f1, F1, S_F1);
    k_pair_layer<<<NAG/64, 512, 0, stream>>>(F1, S_F1, S_F2, W_f2, invRf);
    k_vf_vtop<<<NAG/4, 256, 0, stream>>>(F1, S_F2, SFb, W_ie1, W_ia1,
                                         W_at1, b_at1, VT_IE, VT_IA, invRf);
    // both importance chains fused: XI_E -> XI, XI_A -> X_E (in place)
    k_imp1_both<<<NEE/32, 512, 0, stream>>>(X_E, VT_IE, VT_IA, W_ie1, W_ia1,
                                            XI, S_IE1, S_IA1);
    k_pair_both<<<NBLK_PE64 + NBLK_PE64, 512, 0, stream>>>(
        XI, S_IE1, S_IE2, W_ie2, invRe, X_E, S_IA1, S_IA2, W_ia2, invRe);
    k_imp3_both<<<2*(NEE/16), 256, 0, stream>>>(XI, X_E, S_IE2, S_IA2,
                                                W_ie3, W_ia3, Z_IE, Z_IA,
                                                S_IE3, S_IA3, invRe);

    k_final_small<<<NAG/4, 256, 0, stream>>>(Z_IE, Z_IA, S_IE3, S_IA3, SFb,
                                             W_oa1, b_oa1, W_oa2, b_oa2, out, invRe);
    k_attn<<<NEE/32, 256, 0, stream>>>(F1, ESC, W_at1, W_at2, b_at2,
                                       W_at3, b_at3, out);
}